// Round 3
// baseline (409.503 us; speedup 1.0000x reference)
//
#include <hip/hip_runtime.h>
#include <hip/hip_bf16.h>
#include <math.h>

#define BATCH 8192

typedef unsigned short bf16_t;
typedef __attribute__((ext_vector_type(8))) short short8;
typedef __attribute__((ext_vector_type(4))) float f32x4;

__device__ __forceinline__ float bf2f(bf16_t u) {
    union { unsigned int i; float f; } v; v.i = ((unsigned int)u) << 16; return v.f;
}
__device__ __forceinline__ bf16_t f2bf(float f) {
    union { float f; unsigned int i; } v; v.f = f;
    unsigned int x = v.i;
    unsigned int r = (x + 0x7FFFu + ((x >> 16) & 1u)) >> 16;   // RNE
    return (bf16_t)r;
}
// tanh(x) = sign(x) * (1 - 2/(exp(2|x|)+1)); ~7 VALU ops, err ~1e-6
__device__ __forceinline__ float fast_tanh(float x) {
    float ax = fabsf(x);
    float e = __expf(ax + ax);
    float t = 1.0f - 2.0f * __builtin_amdgcn_rcpf(e + 1.0f);
    return copysignf(t, x);
}

// ---------------------------------------------------------------------------
// K0: weight prep — transpose to [N][K] bf16 (Wt2 K-padded 1584->1600 w/ zeros)
// ---------------------------------------------------------------------------
__global__ __launch_bounds__(256) void k_wprep(
    const float* __restrict__ W0, const float* __restrict__ W1,
    const float* __restrict__ W2,
    bf16_t* __restrict__ Wt0, bf16_t* __restrict__ Wt1, bf16_t* __restrict__ Wt2)
{
    int idx = blockIdx.x * 256 + threadIdx.x;
    if (idx < 96 * 3328) { int n = idx / 3328, k = idx - n * 3328; Wt0[idx] = f2bf(W0[(size_t)k * 96 + n]); }
    if (idx < 96 * 1536) { int n = idx / 1536, k = idx - n * 1536; Wt1[idx] = f2bf(W1[(size_t)k * 96 + n]); }
    if (idx < 128 * 1600) {
        int n = idx / 1600, k = idx - n * 1600;
        Wt2[idx] = (k < 1584) ? f2bf(W2[(size_t)k * 128 + n]) : (bf16_t)0;
    }
}

// ---------------------------------------------------------------------------
// K1: gen-embedding gather + dense proj -> conv0+tanh+pool (LDS f32, + bf16 to
//     global for fc0) -> conv1+tanh+pool -> pooled1 bf16. One sample per block.
// ---------------------------------------------------------------------------
__global__ __launch_bounds__(256) void k_conv_fused(
    const int* __restrict__ sp, const float* __restrict__ dn,
    const float* __restrict__ gen_table, const float* __restrict__ gen_W, const float* __restrict__ gen_b,
    const float* __restrict__ k0, const float* __restrict__ b0,
    const float* __restrict__ k1, const float* __restrict__ b1,
    bf16_t* __restrict__ pooled0, bf16_t* __restrict__ pooled1)
{
    __shared__ float embG[864];
    __shared__ float x0[8 * 420];     // [fi][hp*32+w], stride 420 => exact 2-way (free) banks
    __shared__ float k0s[56], k1s[448];
    __shared__ float b0s[8], b1s[8];
    __shared__ float dloc[13];
    __shared__ int ids[26];
    const int b = blockIdx.x, t = threadIdx.x;

    if (t < 26) ids[t] = sp[b * 26 + t];
    if (t >= 32 && t < 45)  dloc[t - 32] = dn[b * 13 + (t - 32)];
    if (t >= 64 && t < 120) k0s[t - 64] = k0[t - 64];
    if (t >= 120 && t < 128) b0s[t - 120] = b0[t - 120];
    if (t >= 128 && t < 136) b1s[t - 128] = b1[t - 128];
    for (int i = t; i < 448; i += 256) k1s[i] = k1[i];
    __syncthreads();

    // gather gen rows (float2 pairs) + dense proj
    for (int i = t; i < 416; i += 256) {
        int s = i >> 4, d = (i & 15) * 2;
        float2 v = *(const float2*)(gen_table + (size_t)ids[s] * 32 + d);
        embG[s * 32 + d] = v.x; embG[s * 32 + d + 1] = v.y;
    }
    if (t < 32) {
        float a = gen_b[t];
        #pragma unroll
        for (int k = 0; k < 13; k++) a += dloc[k] * gen_W[k * 32 + t];
        embG[832 + t] = a;
    }
    __syncthreads();

    const int half = t >> 7, tt = t & 127;
    const int w = tt >> 2, f0 = (tt & 3) * 2;

    // conv0 + tanh + pool (27 -> 13), thread covers fo pair {f0,f0+1}
    {
        float k0r[7][2];
        #pragma unroll
        for (int tap = 0; tap < 7; tap++) { k0r[tap][0] = k0s[tap * 8 + f0]; k0r[tap][1] = k0s[tap * 8 + f0 + 1]; }
        const int hpb = half ? 7 : 0, hpe = half ? 13 : 7;
        for (int hp = hpb; hp < hpe; hp++) {
            float m0 = -1e30f, m1 = -1e30f;
            #pragma unroll
            for (int rr = 0; rr < 2; rr++) {
                int r = 2 * hp + rr;
                float a0 = b0s[f0], a1 = b0s[f0 + 1];
                #pragma unroll
                for (int tap = 0; tap < 7; tap++) {
                    int hh = r + tap - 3;
                    if (hh >= 0 && hh < 27) {
                        float e = embG[hh * 32 + w];
                        a0 += e * k0r[tap][0];
                        a1 += e * k0r[tap][1];
                    }
                }
                m0 = fmaxf(m0, fast_tanh(a0));
                m1 = fmaxf(m1, fast_tanh(a1));
            }
            x0[f0 * 420 + hp * 32 + w] = m0;
            x0[(f0 + 1) * 420 + hp * 32 + w] = m1;
            unsigned int pk = (unsigned int)f2bf(m0) | ((unsigned int)f2bf(m1) << 16);
            *(unsigned int*)(pooled0 + (size_t)b * 3328 + hp * 256 + w * 8 + f0) = pk;
        }
    }
    __syncthreads();

    // conv1 + tanh + pool (13 -> 6); half splits rows 0..5 / 6..11
    {
        const int rbeg = half ? 6 : 0;
        float acc[6][2];
        #pragma unroll
        for (int j = 0; j < 6; j++) { acc[j][0] = b1s[f0]; acc[j][1] = b1s[f0 + 1]; }
        for (int fi = 0; fi < 8; fi++) {
            float xr[13];
            #pragma unroll
            for (int hh = 0; hh < 13; hh++) xr[hh] = x0[fi * 420 + hh * 32 + w];
            float kr[7][2];
            #pragma unroll
            for (int tap = 0; tap < 7; tap++) { kr[tap][0] = k1s[tap * 64 + fi * 8 + f0]; kr[tap][1] = k1s[tap * 64 + fi * 8 + f0 + 1]; }
            #pragma unroll
            for (int j = 0; j < 6; j++) {
                int r = rbeg + j;
                #pragma unroll
                for (int tap = 0; tap < 7; tap++) {
                    int hh = r + tap - 3;
                    if (hh >= 0 && hh < 13) {
                        acc[j][0] += xr[hh] * kr[tap][0];
                        acc[j][1] += xr[hh] * kr[tap][1];
                    }
                }
            }
        }
        #pragma unroll
        for (int p = 0; p < 3; p++) {
            float m0 = fmaxf(fast_tanh(acc[2 * p][0]), fast_tanh(acc[2 * p + 1][0]));
            float m1 = fmaxf(fast_tanh(acc[2 * p][1]), fast_tanh(acc[2 * p + 1][1]));
            int hp = (rbeg >> 1) + p;
            unsigned int pk = (unsigned int)f2bf(m0) | ((unsigned int)f2bf(m1) << 16);
            *(unsigned int*)(pooled1 + (size_t)b * 1536 + hp * 256 + w * 8 + f0) = pk;
        }
    }
}

// ---------------------------------------------------------------------------
// K2: both fc GEMMs in one launch. z=0: fc0 (K=3328), z=1: fc1 (K=1536).
// grid (M/64, splitK=4, 2). wave = 16 rows x 96 cols; fragments from global.
// ---------------------------------------------------------------------------
__global__ __launch_bounds__(256) void k_fc_mfma(
    const bf16_t* __restrict__ A0, const bf16_t* __restrict__ Wt0, float* __restrict__ P0,
    const bf16_t* __restrict__ A1, const bf16_t* __restrict__ Wt1, float* __restrict__ P1)
{
    const int which = blockIdx.z;
    const bf16_t* A  = which ? A1 : A0;
    const bf16_t* Wt = which ? Wt1 : Wt0;
    float* P = (which ? P1 : P0) + (size_t)blockIdx.y * (BATCH * 96);
    const int K = which ? 1536 : 3328;
    const int iters = which ? 12 : 26;

    const int t = threadIdx.x, w = t >> 6, l = t & 63;
    const int lane15 = l & 15, quad = l >> 4;
    const int rowA = blockIdx.x * 64 + w * 16 + lane15;
    const int kb = blockIdx.y * (K >> 2);

    const bf16_t* ap = A + (size_t)rowA * K + kb + quad * 8;
    const bf16_t* wp = Wt + (size_t)lane15 * K + kb + quad * 8;
    const size_t wstride = (size_t)16 * K;
    f32x4 acc[6] = {};

    #pragma unroll 2
    for (int it = 0; it < iters; it++) {
        short8 a = *(const short8*)(ap + it * 32);
        #pragma unroll
        for (int nt = 0; nt < 6; nt++) {
            short8 bf = *(const short8*)(wp + nt * wstride + it * 32);
            acc[nt] = __builtin_amdgcn_mfma_f32_16x16x32_bf16(a, bf, acc[nt], 0, 0, 0);
        }
    }
    const int baser = blockIdx.x * 64 + w * 16 + quad * 4;
    #pragma unroll
    for (int nt = 0; nt < 6; nt++)
        #pragma unroll
        for (int i = 0; i < 4; i++)
            P[(size_t)(baser + i) * 96 + nt * 16 + lane15] = acc[nt][i];
}

// ---------------------------------------------------------------------------
// K3: build h = [gram_triu(528) | aug(1056) | 16 zeros] bf16, row stride 1600.
// Re-gathers cls embedding from table (L3-resident) + fc epilogues (4 partials).
// ---------------------------------------------------------------------------
__global__ __launch_bounds__(256) void k_build_h(
    const int* __restrict__ sp, const float* __restrict__ dn,
    const float* __restrict__ cls_table, const float* __restrict__ cls_W, const float* __restrict__ cls_b,
    const float* __restrict__ p0, const float* __restrict__ fb0,
    const float* __restrict__ p1, const float* __restrict__ fb1,
    bf16_t* __restrict__ h)
{
    __shared__ float aug[1056];
    __shared__ int ids[26];
    __shared__ float dloc[13];
    const int b = blockIdx.x, t = threadIdx.x;
    if (t < 26) ids[t] = sp[b * 26 + t];
    if (t >= 32 && t < 45) dloc[t - 32] = dn[b * 13 + (t - 32)];
    __syncthreads();

    for (int i = t; i < 416; i += 256) {
        int s = i >> 4, d = (i & 15) * 2;
        float2 v = *(const float2*)(cls_table + (size_t)ids[s] * 32 + d);
        aug[s * 32 + d] = v.x; aug[s * 32 + d + 1] = v.y;
    }
    if (t < 32) {
        float a = cls_b[t];
        #pragma unroll
        for (int k = 0; k < 13; k++) a += dloc[k] * cls_W[k * 32 + t];
        aug[832 + t] = a;
    } else if (t >= 64 && t < 160) {
        int j = t - 64; size_t o = (size_t)b * 96 + j;
        float s = p0[o] + p0[o + 786432] + p0[o + 2 * 786432] + p0[o + 3 * 786432] + fb0[j];
        aug[864 + j] = fast_tanh(s);
    } else if (t >= 160) {
        int j = t - 160; size_t o = (size_t)b * 96 + j;
        float s = p1[o] + p1[o + 786432] + p1[o + 2 * 786432] + p1[o + 3 * 786432] + fb1[j];
        aug[960 + j] = fast_tanh(s);
    }
    __syncthreads();

    bf16_t* hb = h + (size_t)b * 1600;
    for (int i = t; i < 528; i += 256) {
        unsigned int pk = (unsigned int)f2bf(aug[2 * i]) | ((unsigned int)f2bf(aug[2 * i + 1]) << 16);
        *(unsigned int*)(hb + 528 + 2 * i) = pk;
    }
    if (t < 8) *(unsigned int*)(hb + 1584 + 2 * t) = 0u;
    for (int p = t; p < 528; p += 256) {
        int i = 0, rem = p, cnt = 32;
        while (rem >= cnt) { rem -= cnt; cnt--; i++; }
        int j = i + 1 + rem;
        float s = 0.f;
        #pragma unroll
        for (int d = 0; d < 32; d++) s += aug[i * 32 + d] * aug[j * 32 + d];
        hb[p] = f2bf(s);
    }
}

// ---------------------------------------------------------------------------
// K4: MLP: h(8192x1600) @ Wt2^T(128x1600) + relu + BN + outW-dot + sigmoid.
// Block = 16 rows; 4 waves = (nhalf x khalf); in-block split-K via LDS.
// ---------------------------------------------------------------------------
__global__ __launch_bounds__(256) void k_mlp_mfma(
    const bf16_t* __restrict__ h, const bf16_t* __restrict__ Wt2,
    const float* __restrict__ b1, const float* __restrict__ gamma,
    const float* __restrict__ beta, const float* __restrict__ mean,
    const float* __restrict__ var, const float* __restrict__ outW,
    const float* __restrict__ outb, float* __restrict__ out)
{
    __shared__ float lds[2 * 16 * 65];   // [nhalf][row][col], stride 65 (2-way free)
    __shared__ float red2[32];
    const int t = threadIdx.x, w = t >> 6, l = t & 63;
    const int lane15 = l & 15, quad = l >> 4;
    const int nhalf = w & 1, khalf = w >> 1;
    const int rowA = blockIdx.x * 16 + lane15;

    const bf16_t* ap = h + (size_t)rowA * 1600 + khalf * 800 + quad * 8;
    f32x4 acc[4] = {};

    #pragma unroll 2
    for (int it = 0; it < 25; it++) {
        short8 a = *(const short8*)(ap + it * 32);
        #pragma unroll
        for (int nt = 0; nt < 4; nt++) {
            int n = nhalf * 64 + nt * 16 + lane15;
            short8 bf = *(const short8*)(Wt2 + (size_t)n * 1600 + khalf * 800 + it * 32 + quad * 8);
            acc[nt] = __builtin_amdgcn_mfma_f32_16x16x32_bf16(a, bf, acc[nt], 0, 0, 0);
        }
    }

    if (khalf == 1) {
        #pragma unroll
        for (int nt = 0; nt < 4; nt++)
            #pragma unroll
            for (int i = 0; i < 4; i++)
                lds[nhalf * 1040 + (quad * 4 + i) * 65 + nt * 16 + lane15] = acc[nt][i];
    }
    __syncthreads();
    if (khalf == 0) {
        float pl[4] = { 0.f, 0.f, 0.f, 0.f };
        #pragma unroll
        for (int nt = 0; nt < 4; nt++) {
            int c = nhalf * 64 + nt * 16 + lane15;
            float sc = gamma[c] * rsqrtf(var[c] + 1e-3f);
            float sh = beta[c] - mean[c] * sc;
            float ow = outW[c], bb = b1[c];
            #pragma unroll
            for (int i = 0; i < 4; i++) {
                float v = acc[nt][i] + lds[nhalf * 1040 + (quad * 4 + i) * 65 + nt * 16 + lane15] + bb;
                v = fmaxf(v, 0.f);
                pl[i] += (v * sc + sh) * ow;
            }
        }
        #pragma unroll
        for (int m = 1; m < 16; m <<= 1)
            #pragma unroll
            for (int i = 0; i < 4; i++) pl[i] += __shfl_xor(pl[i], m);
        if (lane15 == 0) {
            #pragma unroll
            for (int i = 0; i < 4; i++) red2[(quad * 4 + i) * 2 + nhalf] = pl[i];
        }
    }
    __syncthreads();
    if (t < 16) {
        float s = red2[t * 2] + red2[t * 2 + 1] + outb[0];
        out[blockIdx.x * 16 + t] = 1.f / (1.f + __expf(-s));
    }
}

// ---------------------------------------------------------------------------
extern "C" void kernel_launch(void* const* d_in, const int* in_sizes, int n_in,
                              void* d_out, int out_size, void* d_ws, size_t ws_size,
                              hipStream_t stream) {
    const int*   sp       = (const int*)d_in[0];
    const float* dn       = (const float*)d_in[1];
    const float* gen_tab  = (const float*)d_in[2];
    const float* gen_W    = (const float*)d_in[3];
    const float* gen_b    = (const float*)d_in[4];
    const float* cls_tab  = (const float*)d_in[5];
    const float* cls_W    = (const float*)d_in[6];
    const float* cls_b    = (const float*)d_in[7];
    const float* conv_k0  = (const float*)d_in[8];
    const float* conv_b0  = (const float*)d_in[9];
    const float* fc_W0    = (const float*)d_in[10];
    const float* fc_b0    = (const float*)d_in[11];
    const float* conv_k1  = (const float*)d_in[12];
    const float* conv_b1  = (const float*)d_in[13];
    const float* fc_W1    = (const float*)d_in[14];
    const float* fc_b1    = (const float*)d_in[15];
    const float* mlp_W1   = (const float*)d_in[16];
    const float* mlp_b1   = (const float*)d_in[17];
    const float* bn_gamma = (const float*)d_in[18];
    const float* bn_beta  = (const float*)d_in[19];
    const float* bn_mean  = (const float*)d_in[20];
    const float* bn_var   = (const float*)d_in[21];
    const float* out_W    = (const float*)d_in[22];
    const float* out_b    = (const float*)d_in[23];
    float* out = (float*)d_out;

    // workspace layout (bytes):
    // pooled0 bf16 B*3328*2 = 54,525,952 @ 0   (h bf16 B*1600*2 = 26,214,400 aliases @0)
    // pooled1 bf16 B*1536*2 = 25,165,824 @ 54,525,952
    // p0 f32 4*B*96*4 = 12,582,912 @ 79,691,776
    // p1 f32 4*B*96*4 = 12,582,912 @ 92,274,688
    // Wt0 bf16 638,976 @ 104,857,600
    // Wt1 bf16 294,912 @ 105,496,576
    // Wt2 bf16 409,600 @ 105,791,488  -> end 106,201,088
    char* ws = (char*)d_ws;
    bf16_t* pooled0 = (bf16_t*)(ws + 0);
    bf16_t* pooled1 = (bf16_t*)(ws + 54525952ULL);
    float*  p0      = (float*)(ws + 79691776ULL);
    float*  p1      = (float*)(ws + 92274688ULL);
    bf16_t* Wt0     = (bf16_t*)(ws + 104857600ULL);
    bf16_t* Wt1     = (bf16_t*)(ws + 105496576ULL);
    bf16_t* Wt2     = (bf16_t*)(ws + 105791488ULL);
    bf16_t* h       = (bf16_t*)(ws + 0);   // aliases pooled0 (consumed by fc before build_h)

    k_wprep<<<1248, 256, 0, stream>>>(fc_W0, fc_W1, mlp_W1, Wt0, Wt1, Wt2);
    k_conv_fused<<<BATCH, 256, 0, stream>>>(sp, dn, gen_tab, gen_W, gen_b,
                                            conv_k0, conv_b0, conv_k1, conv_b1,
                                            pooled0, pooled1);
    k_fc_mfma<<<dim3(BATCH / 64, 4, 2), 256, 0, stream>>>(pooled0, Wt0, p0, pooled1, Wt1, p1);
    k_build_h<<<BATCH, 256, 0, stream>>>(sp, dn, cls_tab, cls_W, cls_b,
                                         p0, fc_b0, p1, fc_b1, h);
    k_mlp_mfma<<<BATCH / 16, 256, 0, stream>>>(h, Wt2, mlp_b1, bn_gamma, bn_beta,
                                               bn_mean, bn_var, out_W, out_b, out);
}

// Round 4
// 330.738 us; speedup vs baseline: 1.2381x; 1.2381x over previous
//
#include <hip/hip_runtime.h>
#include <hip/hip_bf16.h>
#include <math.h>

#define BATCH 8192

typedef unsigned short bf16_t;
typedef __attribute__((ext_vector_type(8))) short short8;
typedef __attribute__((ext_vector_type(4))) float f32x4;

__device__ __forceinline__ float bf2f(bf16_t u) {
    union { unsigned int i; float f; } v; v.i = ((unsigned int)u) << 16; return v.f;
}
__device__ __forceinline__ bf16_t f2bf(float f) {
    union { float f; unsigned int i; } v; v.f = f;
    unsigned int x = v.i;
    unsigned int r = (x + 0x7FFFu + ((x >> 16) & 1u)) >> 16;   // RNE
    return (bf16_t)r;
}
// tanh(x) = sign(x) * (1 - 2/(exp(2|x|)+1)); err ~1e-6
__device__ __forceinline__ float fast_tanh(float x) {
    float ax = fabsf(x);
    float e = __expf(ax + ax);
    float t = 1.0f - 2.0f * __builtin_amdgcn_rcpf(e + 1.0f);
    return copysignf(t, x);
}

// ---------------------------------------------------------------------------
// K0: weight prep — transpose to [N][K] bf16 (Wt2 K-padded 1584->1600 w/ zeros)
// ---------------------------------------------------------------------------
__global__ __launch_bounds__(256) void k_wprep(
    const float* __restrict__ W0, const float* __restrict__ W1,
    const float* __restrict__ W2,
    bf16_t* __restrict__ Wt0, bf16_t* __restrict__ Wt1, bf16_t* __restrict__ Wt2)
{
    int idx = blockIdx.x * 256 + threadIdx.x;
    if (idx < 96 * 3328) { int n = idx / 3328, k = idx - n * 3328; Wt0[idx] = f2bf(W0[(size_t)k * 96 + n]); }
    if (idx < 96 * 1536) { int n = idx / 1536, k = idx - n * 1536; Wt1[idx] = f2bf(W1[(size_t)k * 96 + n]); }
    if (idx < 128 * 1600) {
        int n = idx / 1600, k = idx - n * 1600;
        Wt2[idx] = (k < 1584) ? f2bf(W2[(size_t)k * 128 + n]) : (bf16_t)0;
    }
}

// ---------------------------------------------------------------------------
// K1: fused conv path, 2 samples per block (sample picked ONLY via pointer
//     offsets — every loop bound is compile-time).
//     gather+proj -> conv0+tanh+pool -> (LDS bf16 + pooled0 global)
//     -> conv1+tanh+pool -> pooled1 global.
// ---------------------------------------------------------------------------
__global__ __launch_bounds__(256) void k_conv_fused(
    const int* __restrict__ sp, const float* __restrict__ dn,
    const float* __restrict__ gen_table, const float* __restrict__ gen_W, const float* __restrict__ gen_b,
    const float* __restrict__ k0, const float* __restrict__ b0,
    const float* __restrict__ k1, const float* __restrict__ b1,
    bf16_t* __restrict__ pooled0, bf16_t* __restrict__ pooled1)
{
    __shared__ float embG[2 * 864];
    __shared__ unsigned int x0[2 * 13 * 32 * 4];   // bf16-pair words [s][hp][w][q]
    __shared__ float k0s[56], k1s[448], b0s[8], b1s[8];
    __shared__ int ids[52];
    __shared__ float dloc[26];
    const int t = threadIdx.x;
    const int half = t >> 7, tt = t & 127;
    const int b = blockIdx.x * 2 + half;

    if (tt < 26) ids[half * 26 + tt] = sp[b * 26 + tt];
    if (tt >= 32 && tt < 45) dloc[half * 13 + tt - 32] = dn[b * 13 + (tt - 32)];
    if (t < 56) k0s[t] = k0[t];
    if (t >= 64 && t < 72) b0s[t - 64] = b0[t - 64];
    if (t >= 72 && t < 80) b1s[t - 72] = b1[t - 72];
    for (int i = t; i < 448; i += 256) k1s[i] = k1[i];
    __syncthreads();

    // gather gen rows (own sample's 26x32 as float2) + dense proj row 26
    for (int i = tt; i < 416; i += 128) {
        int s_ = i >> 4, d = (i & 15) * 2;
        float2 v = *(const float2*)(gen_table + (size_t)ids[half * 26 + s_] * 32 + d);
        embG[half * 864 + s_ * 32 + d] = v.x;
        embG[half * 864 + s_ * 32 + d + 1] = v.y;
    }
    if (tt < 32) {
        float a = gen_b[tt];
        #pragma unroll
        for (int k = 0; k < 13; k++) a += dloc[half * 13 + k] * gen_W[k * 32 + tt];
        embG[half * 864 + 832 + tt] = a;
    }
    __syncthreads();

    // ---- conv0 + tanh + pool (27 -> 13), thread = (w, fo-pair) over own sample
    {
        const int w = tt >> 2, f0 = (tt & 3) * 2;
        float xr[27];
        #pragma unroll
        for (int h = 0; h < 27; h++) xr[h] = embG[half * 864 + h * 32 + w];
        float k0r[7][2];
        #pragma unroll
        for (int tap = 0; tap < 7; tap++) {
            k0r[tap][0] = k0s[tap * 8 + f0];
            k0r[tap][1] = k0s[tap * 8 + f0 + 1];
        }
        const float b00 = b0s[f0], b01 = b0s[f0 + 1];
        #pragma unroll
        for (int hp = 0; hp < 13; hp++) {
            float m0 = -1e30f, m1 = -1e30f;
            #pragma unroll
            for (int rr = 0; rr < 2; rr++) {
                const int r = 2 * hp + rr;
                float a0 = b00, a1 = b01;
                #pragma unroll
                for (int tap = 0; tap < 7; tap++) {
                    const int hh = r + tap - 3;
                    if (hh >= 0 && hh < 27) {
                        float e = xr[hh];
                        a0 += e * k0r[tap][0];
                        a1 += e * k0r[tap][1];
                    }
                }
                m0 = fmaxf(m0, fast_tanh(a0));
                m1 = fmaxf(m1, fast_tanh(a1));
            }
            unsigned int pk = (unsigned int)f2bf(m0) | ((unsigned int)f2bf(m1) << 16);
            x0[half * 1664 + hp * 128 + w * 4 + (tt & 3)] = pk;
            *(unsigned int*)(pooled0 + (size_t)b * 3328 + hp * 256 + w * 8 + f0) = pk;
        }
    }
    __syncthreads();

    // ---- conv1 + tanh + pool (13 -> 6), thread = (w, fo), both samples
    {
        const int w1 = t >> 3, fo = t & 7;
        float kr[7][8];
        #pragma unroll
        for (int tap = 0; tap < 7; tap++)
            #pragma unroll
            for (int fi = 0; fi < 8; fi++) kr[tap][fi] = k1s[tap * 64 + fi * 8 + fo];
        const float bb = b1s[fo];

        #pragma unroll
        for (int s = 0; s < 2; s++) {
            float acc[12];
            #pragma unroll
            for (int r = 0; r < 12; r++) acc[r] = bb;
            #pragma unroll
            for (int hh = 0; hh < 13; hh++) {
                uint4 v = *(const uint4*)&x0[s * 1664 + hh * 128 + w1 * 4];
                unsigned int vv[4] = { v.x, v.y, v.z, v.w };
                float xf[8];
                #pragma unroll
                for (int q = 0; q < 4; q++) {
                    union { unsigned int i; float f; } lo, hi;
                    lo.i = vv[q] << 16;
                    hi.i = vv[q] & 0xFFFF0000u;
                    xf[2 * q] = lo.f; xf[2 * q + 1] = hi.f;
                }
                #pragma unroll
                for (int tap = 0; tap < 7; tap++) {
                    const int r = hh + 3 - tap;
                    if (r >= 0 && r < 12) {
                        #pragma unroll
                        for (int fi = 0; fi < 8; fi++) acc[r] += xf[fi] * kr[tap][fi];
                    }
                }
            }
            const int bs = blockIdx.x * 2 + s;
            #pragma unroll
            for (int hp = 0; hp < 6; hp++) {
                float m = fmaxf(fast_tanh(acc[2 * hp]), fast_tanh(acc[2 * hp + 1]));
                pooled1[(size_t)bs * 1536 + hp * 256 + w1 * 8 + fo] = f2bf(m);
            }
        }
    }
}

// ---------------------------------------------------------------------------
// K2: both fc GEMMs in one launch. z=0: fc0 (K=3328), z=1: fc1 (K=1536).
// grid (M/64, splitK=4, 2). wave = 16 rows x 96 cols; fragments from global.
// ---------------------------------------------------------------------------
__global__ __launch_bounds__(256) void k_fc_mfma(
    const bf16_t* __restrict__ A0, const bf16_t* __restrict__ Wt0, float* __restrict__ P0,
    const bf16_t* __restrict__ A1, const bf16_t* __restrict__ Wt1, float* __restrict__ P1)
{
    const int which = blockIdx.z;
    const bf16_t* A  = which ? A1 : A0;
    const bf16_t* Wt = which ? Wt1 : Wt0;
    float* P = (which ? P1 : P0) + (size_t)blockIdx.y * (BATCH * 96);
    const int K = which ? 1536 : 3328;
    const int iters = which ? 12 : 26;

    const int t = threadIdx.x, w = t >> 6, l = t & 63;
    const int lane15 = l & 15, quad = l >> 4;
    const int rowA = blockIdx.x * 64 + w * 16 + lane15;
    const int kb = blockIdx.y * (K >> 2);

    const bf16_t* ap = A + (size_t)rowA * K + kb + quad * 8;
    const bf16_t* wp = Wt + (size_t)lane15 * K + kb + quad * 8;
    const size_t wstride = (size_t)16 * K;
    f32x4 acc[6] = {};

    #pragma unroll 2
    for (int it = 0; it < iters; it++) {
        short8 a = *(const short8*)(ap + it * 32);
        #pragma unroll
        for (int nt = 0; nt < 6; nt++) {
            short8 bf = *(const short8*)(wp + nt * wstride + it * 32);
            acc[nt] = __builtin_amdgcn_mfma_f32_16x16x32_bf16(a, bf, acc[nt], 0, 0, 0);
        }
    }
    const int baser = blockIdx.x * 64 + w * 16 + quad * 4;
    #pragma unroll
    for (int nt = 0; nt < 6; nt++)
        #pragma unroll
        for (int i = 0; i < 4; i++)
            P[(size_t)(baser + i) * 96 + nt * 16 + lane15] = acc[nt][i];
}

// ---------------------------------------------------------------------------
// K3: build h = [gram_triu(528) | aug(1056) | 16 zeros] bf16, row stride 1600.
// Re-gathers cls embedding from table (L3-resident) + fc epilogues (4 partials).
// ---------------------------------------------------------------------------
__global__ __launch_bounds__(256) void k_build_h(
    const int* __restrict__ sp, const float* __restrict__ dn,
    const float* __restrict__ cls_table, const float* __restrict__ cls_W, const float* __restrict__ cls_b,
    const float* __restrict__ p0, const float* __restrict__ fb0,
    const float* __restrict__ p1, const float* __restrict__ fb1,
    bf16_t* __restrict__ h)
{
    __shared__ float aug[1056];
    __shared__ int ids[26];
    __shared__ float dloc[13];
    const int b = blockIdx.x, t = threadIdx.x;
    if (t < 26) ids[t] = sp[b * 26 + t];
    if (t >= 32 && t < 45) dloc[t - 32] = dn[b * 13 + (t - 32)];
    __syncthreads();

    for (int i = t; i < 416; i += 256) {
        int s = i >> 4, d = (i & 15) * 2;
        float2 v = *(const float2*)(cls_table + (size_t)ids[s] * 32 + d);
        aug[s * 32 + d] = v.x; aug[s * 32 + d + 1] = v.y;
    }
    if (t < 32) {
        float a = cls_b[t];
        #pragma unroll
        for (int k = 0; k < 13; k++) a += dloc[k] * cls_W[k * 32 + t];
        aug[832 + t] = a;
    } else if (t >= 64 && t < 160) {
        int j = t - 64; size_t o = (size_t)b * 96 + j;
        float s = p0[o] + p0[o + 786432] + p0[o + 2 * 786432] + p0[o + 3 * 786432] + fb0[j];
        aug[864 + j] = fast_tanh(s);
    } else if (t >= 160) {
        int j = t - 160; size_t o = (size_t)b * 96 + j;
        float s = p1[o] + p1[o + 786432] + p1[o + 2 * 786432] + p1[o + 3 * 786432] + fb1[j];
        aug[960 + j] = fast_tanh(s);
    }
    __syncthreads();

    bf16_t* hb = h + (size_t)b * 1600;
    for (int i = t; i < 528; i += 256) {
        unsigned int pk = (unsigned int)f2bf(aug[2 * i]) | ((unsigned int)f2bf(aug[2 * i + 1]) << 16);
        *(unsigned int*)(hb + 528 + 2 * i) = pk;
    }
    if (t < 8) *(unsigned int*)(hb + 1584 + 2 * t) = 0u;
    for (int p = t; p < 528; p += 256) {
        // closed-form triangular row index: start(i) = i*(65-i)/2
        int i = (int)((65.0f - sqrtf(4225.0f - 8.0f * (float)p)) * 0.5f);
        int st = (i * (65 - i)) >> 1;
        if (st > p) { i--; st = (i * (65 - i)) >> 1; }
        else { int st2 = ((i + 1) * (64 - i)) >> 1; if (st2 <= p) { i++; st = st2; } }
        int j = i + 1 + (p - st);
        float s = 0.f;
        #pragma unroll
        for (int d = 0; d < 32; d++) s += aug[i * 32 + d] * aug[j * 32 + d];
        hb[p] = f2bf(s);
    }
}

// ---------------------------------------------------------------------------
// K4: MLP: h(8192x1600) @ Wt2^T(128x1600) + relu + BN + outW-dot + sigmoid.
// Block = 16 rows; 4 waves = (nhalf x khalf); in-block split-K via LDS.
// ---------------------------------------------------------------------------
__global__ __launch_bounds__(256) void k_mlp_mfma(
    const bf16_t* __restrict__ h, const bf16_t* __restrict__ Wt2,
    const float* __restrict__ b1, const float* __restrict__ gamma,
    const float* __restrict__ beta, const float* __restrict__ mean,
    const float* __restrict__ var, const float* __restrict__ outW,
    const float* __restrict__ outb, float* __restrict__ out)
{
    __shared__ float lds[2 * 16 * 65];
    __shared__ float red2[32];
    const int t = threadIdx.x, w = t >> 6, l = t & 63;
    const int lane15 = l & 15, quad = l >> 4;
    const int nhalf = w & 1, khalf = w >> 1;
    const int rowA = blockIdx.x * 16 + lane15;

    const bf16_t* ap = h + (size_t)rowA * 1600 + khalf * 800 + quad * 8;
    f32x4 acc[4] = {};

    #pragma unroll 2
    for (int it = 0; it < 25; it++) {
        short8 a = *(const short8*)(ap + it * 32);
        #pragma unroll
        for (int nt = 0; nt < 4; nt++) {
            int n = nhalf * 64 + nt * 16 + lane15;
            short8 bf = *(const short8*)(Wt2 + (size_t)n * 1600 + khalf * 800 + it * 32 + quad * 8);
            acc[nt] = __builtin_amdgcn_mfma_f32_16x16x32_bf16(a, bf, acc[nt], 0, 0, 0);
        }
    }

    if (khalf == 1) {
        #pragma unroll
        for (int nt = 0; nt < 4; nt++)
            #pragma unroll
            for (int i = 0; i < 4; i++)
                lds[nhalf * 1040 + (quad * 4 + i) * 65 + nt * 16 + lane15] = acc[nt][i];
    }
    __syncthreads();
    if (khalf == 0) {
        float pl[4] = { 0.f, 0.f, 0.f, 0.f };
        #pragma unroll
        for (int nt = 0; nt < 4; nt++) {
            int c = nhalf * 64 + nt * 16 + lane15;
            float sc = gamma[c] * rsqrtf(var[c] + 1e-3f);
            float sh = beta[c] - mean[c] * sc;
            float ow = outW[c], bb = b1[c];
            #pragma unroll
            for (int i = 0; i < 4; i++) {
                float v = acc[nt][i] + lds[nhalf * 1040 + (quad * 4 + i) * 65 + nt * 16 + lane15] + bb;
                v = fmaxf(v, 0.f);
                pl[i] += (v * sc + sh) * ow;
            }
        }
        #pragma unroll
        for (int m = 1; m < 16; m <<= 1)
            #pragma unroll
            for (int i = 0; i < 4; i++) pl[i] += __shfl_xor(pl[i], m);
        if (lane15 == 0) {
            #pragma unroll
            for (int i = 0; i < 4; i++) red2[(quad * 4 + i) * 2 + nhalf] = pl[i];
        }
    }
    __syncthreads();
    if (t < 16) {
        float s = red2[t * 2] + red2[t * 2 + 1] + outb[0];
        out[blockIdx.x * 16 + t] = 1.f / (1.f + __expf(-s));
    }
}

// ---------------------------------------------------------------------------
extern "C" void kernel_launch(void* const* d_in, const int* in_sizes, int n_in,
                              void* d_out, int out_size, void* d_ws, size_t ws_size,
                              hipStream_t stream) {
    const int*   sp       = (const int*)d_in[0];
    const float* dn       = (const float*)d_in[1];
    const float* gen_tab  = (const float*)d_in[2];
    const float* gen_W    = (const float*)d_in[3];
    const float* gen_b    = (const float*)d_in[4];
    const float* cls_tab  = (const float*)d_in[5];
    const float* cls_W    = (const float*)d_in[6];
    const float* cls_b    = (const float*)d_in[7];
    const float* conv_k0  = (const float*)d_in[8];
    const float* conv_b0  = (const float*)d_in[9];
    const float* fc_W0    = (const float*)d_in[10];
    const float* fc_b0    = (const float*)d_in[11];
    const float* conv_k1  = (const float*)d_in[12];
    const float* conv_b1  = (const float*)d_in[13];
    const float* fc_W1    = (const float*)d_in[14];
    const float* fc_b1    = (const float*)d_in[15];
    const float* mlp_W1   = (const float*)d_in[16];
    const float* mlp_b1   = (const float*)d_in[17];
    const float* bn_gamma = (const float*)d_in[18];
    const float* bn_beta  = (const float*)d_in[19];
    const float* bn_mean  = (const float*)d_in[20];
    const float* bn_var   = (const float*)d_in[21];
    const float* out_W    = (const float*)d_in[22];
    const float* out_b    = (const float*)d_in[23];
    float* out = (float*)d_out;

    char* ws = (char*)d_ws;
    bf16_t* pooled0 = (bf16_t*)(ws + 0);
    bf16_t* pooled1 = (bf16_t*)(ws + 54525952ULL);
    float*  p0      = (float*)(ws + 79691776ULL);
    float*  p1      = (float*)(ws + 92274688ULL);
    bf16_t* Wt0     = (bf16_t*)(ws + 104857600ULL);
    bf16_t* Wt1     = (bf16_t*)(ws + 105496576ULL);
    bf16_t* Wt2     = (bf16_t*)(ws + 105791488ULL);
    bf16_t* h       = (bf16_t*)(ws + 0);   // aliases pooled0 (consumed by fc before build_h)

    k_wprep<<<1248, 256, 0, stream>>>(fc_W0, fc_W1, mlp_W1, Wt0, Wt1, Wt2);
    k_conv_fused<<<BATCH / 2, 256, 0, stream>>>(sp, dn, gen_tab, gen_W, gen_b,
                                                conv_k0, conv_b0, conv_k1, conv_b1,
                                                pooled0, pooled1);
    k_fc_mfma<<<dim3(BATCH / 64, 4, 2), 256, 0, stream>>>(pooled0, Wt0, p0, pooled1, Wt1, p1);
    k_build_h<<<BATCH, 256, 0, stream>>>(sp, dn, cls_tab, cls_W, cls_b,
                                         p0, fc_b0, p1, fc_b1, h);
    k_mlp_mfma<<<BATCH / 16, 256, 0, stream>>>(h, Wt2, mlp_b1, bn_gamma, bn_beta,
                                               bn_mean, bn_var, out_W, out_b, out);
}

// Round 5
// 318.857 us; speedup vs baseline: 1.2843x; 1.0373x over previous
//
#include <hip/hip_runtime.h>
#include <hip/hip_bf16.h>
#include <math.h>

#define BATCH 8192

typedef unsigned short bf16_t;
typedef __attribute__((ext_vector_type(8))) short short8;
typedef __attribute__((ext_vector_type(4))) float f32x4;

__device__ __forceinline__ float bf2f(bf16_t u) {
    union { unsigned int i; float f; } v; v.i = ((unsigned int)u) << 16; return v.f;
}
__device__ __forceinline__ bf16_t f2bf(float f) {
    union { float f; unsigned int i; } v; v.f = f;
    unsigned int x = v.i;
    unsigned int r = (x + 0x7FFFu + ((x >> 16) & 1u)) >> 16;   // RNE
    return (bf16_t)r;
}
// tanh(x) = sign(x) * (1 - 2/(exp(2|x|)+1)); err ~1e-6
__device__ __forceinline__ float fast_tanh(float x) {
    float ax = fabsf(x);
    float e = __expf(ax + ax);
    float t = 1.0f - 2.0f * __builtin_amdgcn_rcpf(e + 1.0f);
    return copysignf(t, x);
}

// ---------------------------------------------------------------------------
// K0: weight prep — transpose to [N][K] bf16 (Wt2 K-padded 1584->1600 w/ zeros)
// ---------------------------------------------------------------------------
__global__ __launch_bounds__(256) void k_wprep(
    const float* __restrict__ W0, const float* __restrict__ W1,
    const float* __restrict__ W2,
    bf16_t* __restrict__ Wt0, bf16_t* __restrict__ Wt1, bf16_t* __restrict__ Wt2)
{
    int idx = blockIdx.x * 256 + threadIdx.x;
    if (idx < 96 * 3328) { int n = idx / 3328, k = idx - n * 3328; Wt0[idx] = f2bf(W0[(size_t)k * 96 + n]); }
    if (idx < 96 * 1536) { int n = idx / 1536, k = idx - n * 1536; Wt1[idx] = f2bf(W1[(size_t)k * 96 + n]); }
    if (idx < 128 * 1600) {
        int n = idx / 1600, k = idx - n * 1600;
        Wt2[idx] = (k < 1584) ? f2bf(W2[(size_t)k * 128 + n]) : (bf16_t)0;
    }
}

// ---------------------------------------------------------------------------
// K1: fused conv path, 2 samples per block (sample via pointer offsets only;
//     all loop bounds compile-time). embG transposed [w][h] (stride 28,
//     16B-aligned) so conv0 input is 7x ds_read_b128. tanh AFTER maxpool
//     (monotone) halves transcendentals.
// ---------------------------------------------------------------------------
__global__ __launch_bounds__(256) void k_conv_fused(
    const int* __restrict__ sp, const float* __restrict__ dn,
    const float* __restrict__ gen_table, const float* __restrict__ gen_W, const float* __restrict__ gen_b,
    const float* __restrict__ k0, const float* __restrict__ b0,
    const float* __restrict__ k1, const float* __restrict__ b1,
    bf16_t* __restrict__ pooled0, bf16_t* __restrict__ pooled1)
{
    __shared__ float embGt[2][32][28];             // [s][w][h], h=0..26
    __shared__ unsigned int x0[2 * 13 * 32 * 4];   // bf16-pair words [s][hp][w][q]
    __shared__ float k0s[56], k1s[448], b0s[8], b1s[8];
    __shared__ int ids[52];
    __shared__ float dloc[26];
    const int t = threadIdx.x;
    const int half = t >> 7, tt = t & 127;
    const int b = blockIdx.x * 2 + half;

    if (tt < 26) ids[half * 26 + tt] = sp[b * 26 + tt];
    if (tt >= 32 && tt < 45) dloc[half * 13 + tt - 32] = dn[b * 13 + (tt - 32)];
    if (t < 56) k0s[t] = k0[t];
    if (t >= 64 && t < 72) b0s[t - 64] = b0[t - 64];
    if (t >= 72 && t < 80) b1s[t - 72] = b1[t - 72];
    for (int i = t; i < 448; i += 256) k1s[i] = k1[i];
    __syncthreads();

    // gather gen rows (float2) -> transposed LDS; dense proj -> h=26
    for (int i = tt; i < 416; i += 128) {
        int s_ = i >> 4, d = (i & 15) * 2;
        float2 v = *(const float2*)(gen_table + (size_t)ids[half * 26 + s_] * 32 + d);
        embGt[half][d][s_] = v.x;
        embGt[half][d + 1][s_] = v.y;
    }
    if (tt < 32) {
        float a = gen_b[tt];
        #pragma unroll
        for (int k = 0; k < 13; k++) a += dloc[half * 13 + k] * gen_W[k * 32 + tt];
        embGt[half][tt][26] = a;
    }
    __syncthreads();

    // ---- conv0 + pool + tanh (27 -> 13), thread = (w, fo-pair), own sample
    {
        const int w = tt >> 2, f0 = (tt & 3) * 2;
        const float* xp = &embGt[half][w][0];
        float xr[28];
        #pragma unroll
        for (int q = 0; q < 7; q++) {
            float4 v = *(const float4*)(xp + 4 * q);
            xr[4 * q] = v.x; xr[4 * q + 1] = v.y; xr[4 * q + 2] = v.z; xr[4 * q + 3] = v.w;
        }
        float k0r[7][2];
        #pragma unroll
        for (int tap = 0; tap < 7; tap++) {
            k0r[tap][0] = k0s[tap * 8 + f0];
            k0r[tap][1] = k0s[tap * 8 + f0 + 1];
        }
        const float b00 = b0s[f0], b01 = b0s[f0 + 1];
        #pragma unroll
        for (int hp = 0; hp < 13; hp++) {
            float p00 = b00, p01 = b01, p10 = b00, p11 = b01;
            #pragma unroll
            for (int tap = 0; tap < 7; tap++) {
                const int h0 = 2 * hp + tap - 3;
                if (h0 >= 0 && h0 < 27) {
                    p00 += xr[h0] * k0r[tap][0];
                    p01 += xr[h0] * k0r[tap][1];
                }
                const int h1 = 2 * hp + 1 + tap - 3;
                if (h1 >= 0 && h1 < 27) {
                    p10 += xr[h1] * k0r[tap][0];
                    p11 += xr[h1] * k0r[tap][1];
                }
            }
            float m0 = fast_tanh(fmaxf(p00, p10));
            float m1 = fast_tanh(fmaxf(p01, p11));
            unsigned int pk = (unsigned int)f2bf(m0) | ((unsigned int)f2bf(m1) << 16);
            x0[half * 1664 + hp * 128 + w * 4 + (tt & 3)] = pk;
            *(unsigned int*)(pooled0 + (size_t)b * 3328 + hp * 256 + w * 8 + f0) = pk;
        }
    }
    __syncthreads();

    // ---- conv1 + pool + tanh (13 -> 6), thread = (w, fo), both samples
    {
        const int w1 = t >> 3, fo = t & 7;
        float kr[7][8];
        #pragma unroll
        for (int tap = 0; tap < 7; tap++)
            #pragma unroll
            for (int fi = 0; fi < 8; fi++) kr[tap][fi] = k1s[tap * 64 + fi * 8 + fo];
        const float bb = b1s[fo];

        #pragma unroll
        for (int s = 0; s < 2; s++) {
            float acc[12];
            #pragma unroll
            for (int r = 0; r < 12; r++) acc[r] = bb;
            #pragma unroll
            for (int hh = 0; hh < 13; hh++) {
                uint4 v = *(const uint4*)&x0[s * 1664 + hh * 128 + w1 * 4];
                unsigned int vv[4] = { v.x, v.y, v.z, v.w };
                float xf[8];
                #pragma unroll
                for (int q = 0; q < 4; q++) {
                    union { unsigned int i; float f; } lo, hi;
                    lo.i = vv[q] << 16;
                    hi.i = vv[q] & 0xFFFF0000u;
                    xf[2 * q] = lo.f; xf[2 * q + 1] = hi.f;
                }
                #pragma unroll
                for (int tap = 0; tap < 7; tap++) {
                    const int r = hh + 3 - tap;
                    if (r >= 0 && r < 12) {
                        #pragma unroll
                        for (int fi = 0; fi < 8; fi++) acc[r] += xf[fi] * kr[tap][fi];
                    }
                }
            }
            const int bs = blockIdx.x * 2 + s;
            #pragma unroll
            for (int hp = 0; hp < 6; hp++) {
                float m = fast_tanh(fmaxf(acc[2 * hp], acc[2 * hp + 1]));
                pooled1[(size_t)bs * 1536 + hp * 256 + w1 * 8 + fo] = f2bf(m);
            }
        }
    }
}

// ---------------------------------------------------------------------------
// K2: both fc GEMMs in one launch. z=0: fc0 (K=3328), z=1: fc1 (K=1536).
// grid (M/64, splitK=4, 2). wave = 16 rows x 96 cols; fragments from global.
// ---------------------------------------------------------------------------
__global__ __launch_bounds__(256) void k_fc_mfma(
    const bf16_t* __restrict__ A0, const bf16_t* __restrict__ Wt0, float* __restrict__ P0,
    const bf16_t* __restrict__ A1, const bf16_t* __restrict__ Wt1, float* __restrict__ P1)
{
    const int which = blockIdx.z;
    const bf16_t* A  = which ? A1 : A0;
    const bf16_t* Wt = which ? Wt1 : Wt0;
    float* P = (which ? P1 : P0) + (size_t)blockIdx.y * (BATCH * 96);
    const int K = which ? 1536 : 3328;
    const int iters = which ? 12 : 26;

    const int t = threadIdx.x, w = t >> 6, l = t & 63;
    const int lane15 = l & 15, quad = l >> 4;
    const int rowA = blockIdx.x * 64 + w * 16 + lane15;
    const int kb = blockIdx.y * (K >> 2);

    const bf16_t* ap = A + (size_t)rowA * K + kb + quad * 8;
    const bf16_t* wp = Wt + (size_t)lane15 * K + kb + quad * 8;
    const size_t wstride = (size_t)16 * K;
    f32x4 acc[6] = {};

    #pragma unroll 2
    for (int it = 0; it < iters; it++) {
        short8 a = *(const short8*)(ap + it * 32);
        #pragma unroll
        for (int nt = 0; nt < 6; nt++) {
            short8 bf = *(const short8*)(wp + nt * wstride + it * 32);
            acc[nt] = __builtin_amdgcn_mfma_f32_16x16x32_bf16(a, bf, acc[nt], 0, 0, 0);
        }
    }
    const int baser = blockIdx.x * 64 + w * 16 + quad * 4;
    #pragma unroll
    for (int nt = 0; nt < 6; nt++)
        #pragma unroll
        for (int i = 0; i < 4; i++)
            P[(size_t)(baser + i) * 96 + nt * 16 + lane15] = acc[nt][i];
}

// ---------------------------------------------------------------------------
// K3: build h = [gram_triu(528) | aug(1056) | 16 zeros] bf16, row stride 1600.
// aug LDS stride 33 -> gram column reads are conflict-free ((i+d)%32 banks).
// Pairs of gram entries per thread -> dword stores, shared row-i loads.
// ---------------------------------------------------------------------------
__global__ __launch_bounds__(256) void k_build_h(
    const int* __restrict__ sp, const float* __restrict__ dn,
    const float* __restrict__ cls_table, const float* __restrict__ cls_W, const float* __restrict__ cls_b,
    const float* __restrict__ p0, const float* __restrict__ fb0,
    const float* __restrict__ p1, const float* __restrict__ fb1,
    bf16_t* __restrict__ h)
{
    __shared__ float aug[33 * 33];   // row stride 33
    __shared__ int ids[26];
    __shared__ float dloc[13];
    const int b = blockIdx.x, t = threadIdx.x;
    if (t < 26) ids[t] = sp[b * 26 + t];
    if (t >= 32 && t < 45) dloc[t - 32] = dn[b * 13 + (t - 32)];
    __syncthreads();

    for (int i = t; i < 416; i += 256) {
        int s = i >> 4, d = (i & 15) * 2;
        float2 v = *(const float2*)(cls_table + (size_t)ids[s] * 32 + d);
        aug[s * 33 + d] = v.x; aug[s * 33 + d + 1] = v.y;
    }
    if (t < 32) {
        float a = cls_b[t];
        #pragma unroll
        for (int k = 0; k < 13; k++) a += dloc[k] * cls_W[k * 32 + t];
        aug[26 * 33 + t] = a;
    } else if (t >= 64 && t < 160) {
        int j = t - 64; size_t o = (size_t)b * 96 + j;
        float s = p0[o] + p0[o + 786432] + p0[o + 2 * 786432] + p0[o + 3 * 786432] + fb0[j];
        int n = 27 + (j >> 5), d = j & 31;
        aug[n * 33 + d] = fast_tanh(s);
    } else if (t >= 160) {
        int j = t - 160; size_t o = (size_t)b * 96 + j;
        float s = p1[o] + p1[o + 786432] + p1[o + 2 * 786432] + p1[o + 3 * 786432] + fb1[j];
        int n = 30 + (j >> 5), d = j & 31;
        aug[n * 33 + d] = fast_tanh(s);
    }
    __syncthreads();

    bf16_t* hb = h + (size_t)b * 1600;
    // aug flat copy (bf16 pairs)
    for (int i = t; i < 528; i += 256) {
        int n = i >> 4, d = (i & 15) * 2;
        unsigned int pk = (unsigned int)f2bf(aug[n * 33 + d]) | ((unsigned int)f2bf(aug[n * 33 + d + 1]) << 16);
        *(unsigned int*)(hb + 528 + 2 * i) = pk;
    }
    if (t < 8) *(unsigned int*)(hb + 1584 + 2 * t) = 0u;

    // gram triu: 264 pairs, dword stores
    for (int pp = t; pp < 264; pp += 256) {
        int p = 2 * pp;
        int i = (int)((65.0f - sqrtf(4225.0f - 8.0f * (float)p)) * 0.5f);
        int st = (i * (65 - i)) >> 1;
        if (st > p) { i--; st = (i * (65 - i)) >> 1; }
        else { int st2 = ((i + 1) * (64 - i)) >> 1; if (st2 <= p) { i++; st = st2; } }
        int j = i + 1 + (p - st);
        float s0 = 0.f, s1 = 0.f;
        if (j < 32) {           // second of pair in same row: (i, j+1)
            #pragma unroll
            for (int d = 0; d < 32; d++) {
                float ai = aug[i * 33 + d];
                s0 += ai * aug[j * 33 + d];
                s1 += ai * aug[(j + 1) * 33 + d];
            }
        } else {                // row wrap: (i,32) then (i+1, i+2)
            #pragma unroll
            for (int d = 0; d < 32; d++) {
                s0 += aug[i * 33 + d] * aug[32 * 33 + d];
                s1 += aug[(i + 1) * 33 + d] * aug[(i + 2) * 33 + d];
            }
        }
        unsigned int pk = (unsigned int)f2bf(s0) | ((unsigned int)f2bf(s1) << 16);
        *(unsigned int*)(hb + p) = pk;
    }
}

// ---------------------------------------------------------------------------
// K4: MLP: h(8192x1600) @ Wt2^T(128x1600) + relu + BN + outW-dot + sigmoid.
// Block = 16 rows; 4 waves = (nhalf x khalf); in-block split-K via LDS.
// ---------------------------------------------------------------------------
__global__ __launch_bounds__(256) void k_mlp_mfma(
    const bf16_t* __restrict__ h, const bf16_t* __restrict__ Wt2,
    const float* __restrict__ b1, const float* __restrict__ gamma,
    const float* __restrict__ beta, const float* __restrict__ mean,
    const float* __restrict__ var, const float* __restrict__ outW,
    const float* __restrict__ outb, float* __restrict__ out)
{
    __shared__ float lds[2 * 16 * 65];
    __shared__ float red2[32];
    const int t = threadIdx.x, w = t >> 6, l = t & 63;
    const int lane15 = l & 15, quad = l >> 4;
    const int nhalf = w & 1, khalf = w >> 1;
    const int rowA = blockIdx.x * 16 + lane15;

    const bf16_t* ap = h + (size_t)rowA * 1600 + khalf * 800 + quad * 8;
    f32x4 acc[4] = {};

    #pragma unroll 2
    for (int it = 0; it < 25; it++) {
        short8 a = *(const short8*)(ap + it * 32);
        #pragma unroll
        for (int nt = 0; nt < 4; nt++) {
            int n = nhalf * 64 + nt * 16 + lane15;
            short8 bf = *(const short8*)(Wt2 + (size_t)n * 1600 + khalf * 800 + it * 32 + quad * 8);
            acc[nt] = __builtin_amdgcn_mfma_f32_16x16x32_bf16(a, bf, acc[nt], 0, 0, 0);
        }
    }

    if (khalf == 1) {
        #pragma unroll
        for (int nt = 0; nt < 4; nt++)
            #pragma unroll
            for (int i = 0; i < 4; i++)
                lds[nhalf * 1040 + (quad * 4 + i) * 65 + nt * 16 + lane15] = acc[nt][i];
    }
    __syncthreads();
    if (khalf == 0) {
        float pl[4] = { 0.f, 0.f, 0.f, 0.f };
        #pragma unroll
        for (int nt = 0; nt < 4; nt++) {
            int c = nhalf * 64 + nt * 16 + lane15;
            float sc = gamma[c] * rsqrtf(var[c] + 1e-3f);
            float sh = beta[c] - mean[c] * sc;
            float ow = outW[c], bb = b1[c];
            #pragma unroll
            for (int i = 0; i < 4; i++) {
                float v = acc[nt][i] + lds[nhalf * 1040 + (quad * 4 + i) * 65 + nt * 16 + lane15] + bb;
                v = fmaxf(v, 0.f);
                pl[i] += (v * sc + sh) * ow;
            }
        }
        #pragma unroll
        for (int m = 1; m < 16; m <<= 1)
            #pragma unroll
            for (int i = 0; i < 4; i++) pl[i] += __shfl_xor(pl[i], m);
        if (lane15 == 0) {
            #pragma unroll
            for (int i = 0; i < 4; i++) red2[(quad * 4 + i) * 2 + nhalf] = pl[i];
        }
    }
    __syncthreads();
    if (t < 16) {
        float s = red2[t * 2] + red2[t * 2 + 1] + outb[0];
        out[blockIdx.x * 16 + t] = 1.f / (1.f + __expf(-s));
    }
}

// ---------------------------------------------------------------------------
extern "C" void kernel_launch(void* const* d_in, const int* in_sizes, int n_in,
                              void* d_out, int out_size, void* d_ws, size_t ws_size,
                              hipStream_t stream) {
    const int*   sp       = (const int*)d_in[0];
    const float* dn       = (const float*)d_in[1];
    const float* gen_tab  = (const float*)d_in[2];
    const float* gen_W    = (const float*)d_in[3];
    const float* gen_b    = (const float*)d_in[4];
    const float* cls_tab  = (const float*)d_in[5];
    const float* cls_W    = (const float*)d_in[6];
    const float* cls_b    = (const float*)d_in[7];
    const float* conv_k0  = (const float*)d_in[8];
    const float* conv_b0  = (const float*)d_in[9];
    const float* fc_W0    = (const float*)d_in[10];
    const float* fc_b0    = (const float*)d_in[11];
    const float* conv_k1  = (const float*)d_in[12];
    const float* conv_b1  = (const float*)d_in[13];
    const float* fc_W1    = (const float*)d_in[14];
    const float* fc_b1    = (const float*)d_in[15];
    const float* mlp_W1   = (const float*)d_in[16];
    const float* mlp_b1   = (const float*)d_in[17];
    const float* bn_gamma = (const float*)d_in[18];
    const float* bn_beta  = (const float*)d_in[19];
    const float* bn_mean  = (const float*)d_in[20];
    const float* bn_var   = (const float*)d_in[21];
    const float* out_W    = (const float*)d_in[22];
    const float* out_b    = (const float*)d_in[23];
    float* out = (float*)d_out;

    char* ws = (char*)d_ws;
    bf16_t* pooled0 = (bf16_t*)(ws + 0);
    bf16_t* pooled1 = (bf16_t*)(ws + 54525952ULL);
    float*  p0      = (float*)(ws + 79691776ULL);
    float*  p1      = (float*)(ws + 92274688ULL);
    bf16_t* Wt0     = (bf16_t*)(ws + 104857600ULL);
    bf16_t* Wt1     = (bf16_t*)(ws + 105496576ULL);
    bf16_t* Wt2     = (bf16_t*)(ws + 105791488ULL);
    bf16_t* h       = (bf16_t*)(ws + 0);   // aliases pooled0 (consumed by fc before build_h)

    k_wprep<<<1248, 256, 0, stream>>>(fc_W0, fc_W1, mlp_W1, Wt0, Wt1, Wt2);
    k_conv_fused<<<BATCH / 2, 256, 0, stream>>>(sp, dn, gen_tab, gen_W, gen_b,
                                                conv_k0, conv_b0, conv_k1, conv_b1,
                                                pooled0, pooled1);
    k_fc_mfma<<<dim3(BATCH / 64, 4, 2), 256, 0, stream>>>(pooled0, Wt0, p0, pooled1, Wt1, p1);
    k_build_h<<<BATCH, 256, 0, stream>>>(sp, dn, cls_tab, cls_W, cls_b,
                                         p0, fc_b0, p1, fc_b1, h);
    k_mlp_mfma<<<BATCH / 16, 256, 0, stream>>>(h, Wt2, mlp_b1, bn_gamma, bn_beta,
                                               bn_mean, bn_var, out_W, out_b, out);
}

// Round 6
// 287.562 us; speedup vs baseline: 1.4241x; 1.1088x over previous
//
#include <hip/hip_runtime.h>
#include <hip/hip_bf16.h>
#include <math.h>

#define BATCH 8192

typedef unsigned short bf16_t;
typedef _Float16 f16_t;
typedef __attribute__((ext_vector_type(2))) _Float16 h2_t;
typedef __attribute__((ext_vector_type(8))) short short8;
typedef __attribute__((ext_vector_type(4))) float f32x4;

union U32H2 { unsigned int u; h2_t h; };

__device__ __forceinline__ float bf2f(bf16_t u) {
    union { unsigned int i; float f; } v; v.i = ((unsigned int)u) << 16; return v.f;
}
__device__ __forceinline__ bf16_t f2bf(float f) {
    union { float f; unsigned int i; } v; v.f = f;
    unsigned int x = v.i;
    unsigned int r = (x + 0x7FFFu + ((x >> 16) & 1u)) >> 16;   // RNE
    return (bf16_t)r;
}
// tanh(x) = sign(x) * (1 - 2/(exp(2|x|)+1)); err ~1e-6
__device__ __forceinline__ float fast_tanh(float x) {
    float ax = fabsf(x);
    float e = __expf(ax + ax);
    float t = 1.0f - 2.0f * __builtin_amdgcn_rcpf(e + 1.0f);
    return copysignf(t, x);
}

// ---------------------------------------------------------------------------
// K0: weight transpose via LDS tiles (coalesced read AND write).
// grid (52, 3): y selects matrix; 64-k tiles.
// ---------------------------------------------------------------------------
__global__ __launch_bounds__(256) void k_wtrans(
    const float* __restrict__ W0, const float* __restrict__ W1, const float* __restrict__ W2,
    bf16_t* __restrict__ Wt0, bf16_t* __restrict__ Wt1, bf16_t* __restrict__ Wt2)
{
    __shared__ float tile[64 * 129];
    const int m = blockIdx.y, t = threadIdx.x;
    const float* src; bf16_t* dst; int Ks, Kd, N, tiles;
    if (m == 0)      { src = W0; dst = Wt0; Ks = 3328; Kd = 3328; N = 96;  tiles = 52; }
    else if (m == 1) { src = W1; dst = Wt1; Ks = 1536; Kd = 1536; N = 96;  tiles = 24; }
    else             { src = W2; dst = Wt2; Ks = 1584; Kd = 1600; N = 128; tiles = 25; }
    if (blockIdx.x >= tiles) return;
    const int k0 = blockIdx.x * 64;
    const int nv = N >> 2;
    for (int i = t; i < 64 * nv; i += 256) {
        int r = i / nv, c4 = i - r * nv;
        int k = k0 + r;
        float4 v = make_float4(0.f, 0.f, 0.f, 0.f);
        if (k < Ks) v = *(const float4*)(src + (size_t)k * N + c4 * 4);
        tile[r * 129 + c4 * 4 + 0] = v.x;
        tile[r * 129 + c4 * 4 + 1] = v.y;
        tile[r * 129 + c4 * 4 + 2] = v.z;
        tile[r * 129 + c4 * 4 + 3] = v.w;
    }
    __syncthreads();
    for (int i = t; i < N * 32; i += 256) {
        int n = i >> 5, j = i & 31;
        unsigned int pk = (unsigned int)f2bf(tile[(2 * j) * 129 + n])
                        | ((unsigned int)f2bf(tile[(2 * j + 1) * 129 + n]) << 16);
        *(unsigned int*)(dst + (size_t)n * Kd + k0 + 2 * j) = pk;
    }
}

// ---------------------------------------------------------------------------
// K1: fused conv path, 2 samples/block. conv0 f32 (LDS-transposed input,
//     b128 reads); conv1 in packed f16 (v_pk_fma_f16), x0 staged as f16 pairs.
// ---------------------------------------------------------------------------
__global__ __launch_bounds__(256) void k_conv_fused(
    const int* __restrict__ sp, const float* __restrict__ dn,
    const float* __restrict__ gen_table, const float* __restrict__ gen_W, const float* __restrict__ gen_b,
    const float* __restrict__ k0, const float* __restrict__ b0,
    const float* __restrict__ k1, const float* __restrict__ b1,
    bf16_t* __restrict__ pooled0, bf16_t* __restrict__ pooled1)
{
    __shared__ float embGt[2][32][28];             // [s][w][h], h=0..26
    __shared__ unsigned int x0[2 * 13 * 32 * 4];   // f16-pair words [s][hp][w][q]
    __shared__ float k0s[56], k1s[448], b0s[8], b1s[8];
    __shared__ int ids[52];
    __shared__ float dloc[26];
    const int t = threadIdx.x;
    const int half = t >> 7, tt = t & 127;
    const int b = blockIdx.x * 2 + half;

    if (tt < 26) ids[half * 26 + tt] = sp[b * 26 + tt];
    if (tt >= 32 && tt < 45) dloc[half * 13 + tt - 32] = dn[b * 13 + (tt - 32)];
    if (t < 56) k0s[t] = k0[t];
    if (t >= 64 && t < 72) b0s[t - 64] = b0[t - 64];
    if (t >= 72 && t < 80) b1s[t - 72] = b1[t - 72];
    for (int i = t; i < 448; i += 256) k1s[i] = k1[i];
    __syncthreads();

    for (int i = tt; i < 416; i += 128) {
        int s_ = i >> 4, d = (i & 15) * 2;
        float2 v = *(const float2*)(gen_table + (size_t)ids[half * 26 + s_] * 32 + d);
        embGt[half][d][s_] = v.x;
        embGt[half][d + 1][s_] = v.y;
    }
    if (tt < 32) {
        float a = gen_b[tt];
        #pragma unroll
        for (int k = 0; k < 13; k++) a += dloc[half * 13 + k] * gen_W[k * 32 + tt];
        embGt[half][tt][26] = a;
    }
    __syncthreads();

    // ---- conv0 + pool + tanh (27 -> 13)
    {
        const int w = tt >> 2, f0 = (tt & 3) * 2;
        const float* xp = &embGt[half][w][0];
        float xr[28];
        #pragma unroll
        for (int q = 0; q < 7; q++) {
            float4 v = *(const float4*)(xp + 4 * q);
            xr[4 * q] = v.x; xr[4 * q + 1] = v.y; xr[4 * q + 2] = v.z; xr[4 * q + 3] = v.w;
        }
        float k0r[7][2];
        #pragma unroll
        for (int tap = 0; tap < 7; tap++) {
            k0r[tap][0] = k0s[tap * 8 + f0];
            k0r[tap][1] = k0s[tap * 8 + f0 + 1];
        }
        const float b00 = b0s[f0], b01 = b0s[f0 + 1];
        #pragma unroll
        for (int hp = 0; hp < 13; hp++) {
            float p00 = b00, p01 = b01, p10 = b00, p11 = b01;
            #pragma unroll
            for (int tap = 0; tap < 7; tap++) {
                const int h0 = 2 * hp + tap - 3;
                if (h0 >= 0 && h0 < 27) {
                    p00 += xr[h0] * k0r[tap][0];
                    p01 += xr[h0] * k0r[tap][1];
                }
                const int h1 = 2 * hp + 1 + tap - 3;
                if (h1 >= 0 && h1 < 27) {
                    p10 += xr[h1] * k0r[tap][0];
                    p11 += xr[h1] * k0r[tap][1];
                }
            }
            float m0 = fast_tanh(fmaxf(p00, p10));
            float m1 = fast_tanh(fmaxf(p01, p11));
            unsigned int pk = (unsigned int)f2bf(m0) | ((unsigned int)f2bf(m1) << 16);
            *(unsigned int*)(pooled0 + (size_t)b * 3328 + hp * 256 + w * 8 + f0) = pk;
            U32H2 hx; hx.h = h2_t{(f16_t)m0, (f16_t)m1};
            x0[half * 1664 + hp * 128 + w * 4 + (tt & 3)] = hx.u;
        }
    }
    __syncthreads();

    // ---- conv1 + pool + tanh (13 -> 6), packed f16
    {
        const int w1 = t >> 3, fo = t & 7;
        h2_t kh[7][4];
        #pragma unroll
        for (int tap = 0; tap < 7; tap++)
            #pragma unroll
            for (int q = 0; q < 4; q++)
                kh[tap][q] = h2_t{(f16_t)k1s[tap * 64 + (2 * q) * 8 + fo],
                                  (f16_t)k1s[tap * 64 + (2 * q + 1) * 8 + fo]};
        const f16_t bbh = (f16_t)b1s[fo];

        #pragma unroll
        for (int s = 0; s < 2; s++) {
            h2_t acc[12];
            #pragma unroll
            for (int r = 0; r < 12; r++) acc[r] = h2_t{bbh, (f16_t)0.f};
            #pragma unroll
            for (int hh = 0; hh < 13; hh++) {
                uint4 v = *(const uint4*)&x0[s * 1664 + hh * 128 + w1 * 4];
                U32H2 c0, c1, c2, c3;
                c0.u = v.x; c1.u = v.y; c2.u = v.z; c3.u = v.w;
                h2_t x2[4] = { c0.h, c1.h, c2.h, c3.h };
                #pragma unroll
                for (int tap = 0; tap < 7; tap++) {
                    const int r = hh + 3 - tap;
                    if (r >= 0 && r < 12) {
                        #pragma unroll
                        for (int q = 0; q < 4; q++) acc[r] += x2[q] * kh[tap][q];
                    }
                }
            }
            const int bs = blockIdx.x * 2 + s;
            #pragma unroll
            for (int hp = 0; hp < 6; hp++) {
                float a0 = (float)acc[2 * hp][0] + (float)acc[2 * hp][1];
                float a1 = (float)acc[2 * hp + 1][0] + (float)acc[2 * hp + 1][1];
                float m = fast_tanh(fmaxf(a0, a1));
                pooled1[(size_t)bs * 1536 + hp * 256 + w1 * 8 + fo] = f2bf(m);
            }
        }
    }
}

// ---------------------------------------------------------------------------
// K2: both fc GEMMs in one launch (unchanged).
// ---------------------------------------------------------------------------
__global__ __launch_bounds__(256) void k_fc_mfma(
    const bf16_t* __restrict__ A0, const bf16_t* __restrict__ Wt0, float* __restrict__ P0,
    const bf16_t* __restrict__ A1, const bf16_t* __restrict__ Wt1, float* __restrict__ P1)
{
    const int which = blockIdx.z;
    const bf16_t* A  = which ? A1 : A0;
    const bf16_t* Wt = which ? Wt1 : Wt0;
    float* P = (which ? P1 : P0) + (size_t)blockIdx.y * (BATCH * 96);
    const int K = which ? 1536 : 3328;
    const int iters = which ? 12 : 26;

    const int t = threadIdx.x, w = t >> 6, l = t & 63;
    const int lane15 = l & 15, quad = l >> 4;
    const int rowA = blockIdx.x * 64 + w * 16 + lane15;
    const int kb = blockIdx.y * (K >> 2);

    const bf16_t* ap = A + (size_t)rowA * K + kb + quad * 8;
    const bf16_t* wp = Wt + (size_t)lane15 * K + kb + quad * 8;
    const size_t wstride = (size_t)16 * K;
    f32x4 acc[6] = {};

    #pragma unroll 2
    for (int it = 0; it < iters; it++) {
        short8 a = *(const short8*)(ap + it * 32);
        #pragma unroll
        for (int nt = 0; nt < 6; nt++) {
            short8 bf = *(const short8*)(wp + nt * wstride + it * 32);
            acc[nt] = __builtin_amdgcn_mfma_f32_16x16x32_bf16(a, bf, acc[nt], 0, 0, 0);
        }
    }
    const int baser = blockIdx.x * 64 + w * 16 + quad * 4;
    #pragma unroll
    for (int nt = 0; nt < 6; nt++)
        #pragma unroll
        for (int i = 0; i < 4; i++)
            P[(size_t)(baser + i) * 96 + nt * 16 + lane15] = acc[nt][i];
}

// ---------------------------------------------------------------------------
// K3: build h. One sample per WAVE (4/block, no __syncthreads).
// gram(33x33) via 3x mfma_16x16x32_bf16 + VALU edge col; triu extract from LDS.
// ---------------------------------------------------------------------------
__global__ __launch_bounds__(256) void k_build_h(
    const int* __restrict__ sp, const float* __restrict__ dn,
    const float* __restrict__ cls_table, const float* __restrict__ cls_W, const float* __restrict__ cls_b,
    const float* __restrict__ p0, const float* __restrict__ fb0,
    const float* __restrict__ p1, const float* __restrict__ fb1,
    bf16_t* __restrict__ h)
{
    __shared__ bf16_t augs[4][33][40];   // row stride 40 (80B, 16B-aligned)
    __shared__ float grams[4][32][34];   // cols 0..32 used (32 = edge)
    const int t = threadIdx.x, wv = t >> 6, l = t & 63;
    const int b = blockIdx.x * 4 + wv;
    bf16_t (*aug)[40] = augs[wv];
    float (*gram)[34] = grams[wv];

    const int myid = (l < 26) ? sp[b * 26 + l] : 0;

    // gather cls rows 0..25 (bf16 pairs)
    for (int i = l; i < 416; i += 64) {
        int s_ = i >> 4, d = (i & 15) * 2;
        int id = __shfl(myid, s_);
        float2 v = *(const float2*)(cls_table + (size_t)id * 32 + d);
        unsigned int pk = (unsigned int)f2bf(v.x) | ((unsigned int)f2bf(v.y) << 16);
        *(unsigned int*)&aug[s_][d] = pk;
    }
    // dense proj -> row 26
    if (l < 32) {
        float a = cls_b[l];
        #pragma unroll
        for (int k = 0; k < 13; k++) a += dn[b * 13 + k] * cls_W[k * 32 + l];
        aug[26][l] = f2bf(a);
    }
    // fc epilogues -> rows 27..32
    for (int i = l; i < 192; i += 64) {
        int n = 27 + (i >> 5), d = i & 31;
        float s;
        if (i < 96) {
            size_t o = (size_t)b * 96 + i;
            s = p0[o] + p0[o + 786432] + p0[o + 2 * 786432] + p0[o + 3 * 786432] + fb0[i];
        } else {
            int j = i - 96; size_t o = (size_t)b * 96 + j;
            s = p1[o] + p1[o + 786432] + p1[o + 2 * 786432] + p1[o + 3 * 786432] + fb1[j];
        }
        aug[n][d] = f2bf(fast_tanh(s));
    }

    // gram via MFMA: tiles (0,0),(0,1),(1,1)
    const int m16 = l & 15, quad = l >> 4;
    short8 a0 = *(const short8*)&aug[m16][quad * 8];
    short8 a1 = *(const short8*)&aug[16 + m16][quad * 8];
    f32x4 c00 = {}, c01 = {}, c11 = {};
    c00 = __builtin_amdgcn_mfma_f32_16x16x32_bf16(a0, a0, c00, 0, 0, 0);
    c01 = __builtin_amdgcn_mfma_f32_16x16x32_bf16(a0, a1, c01, 0, 0, 0);
    c11 = __builtin_amdgcn_mfma_f32_16x16x32_bf16(a1, a1, c11, 0, 0, 0);
    #pragma unroll
    for (int i = 0; i < 4; i++) {
        gram[quad * 4 + i][m16] = c00[i];
        gram[quad * 4 + i][16 + m16] = c01[i];
        gram[16 + quad * 4 + i][16 + m16] = c11[i];
    }
    // edge col 32: (i,32) dots
    if (l < 32) {
        float s = 0.f;
        #pragma unroll
        for (int kk = 0; kk < 16; kk++) {
            unsigned int x = *(const unsigned int*)&aug[l][2 * kk];
            unsigned int y = *(const unsigned int*)&aug[32][2 * kk];
            s += bf2f((bf16_t)(x & 0xFFFFu)) * bf2f((bf16_t)(y & 0xFFFFu));
            s += bf2f((bf16_t)(x >> 16)) * bf2f((bf16_t)(y >> 16));
        }
        gram[l][32] = s;
    }

    bf16_t* hb = h + (size_t)b * 1600;
    // aug flat copy (bf16 already)
    for (int idx = l; idx < 528; idx += 64) {
        int n = idx >> 4, d = (idx & 15) * 2;
        *(unsigned int*)(hb + 528 + 2 * idx) = *(const unsigned int*)&aug[n][d];
    }
    if (l < 8) *(unsigned int*)(hb + 1584 + 2 * l) = 0u;
    // triu extract, 264 dword pairs
    for (int pp = l; pp < 264; pp += 64) {
        int p = 2 * pp;
        int i = (int)((65.0f - sqrtf(4225.0f - 8.0f * (float)p)) * 0.5f);
        int st = (i * (65 - i)) >> 1;
        if (st > p) { i--; st = (i * (65 - i)) >> 1; }
        else { int st2 = ((i + 1) * (64 - i)) >> 1; if (st2 <= p) { i++; st = st2; } }
        int j = i + 1 + (p - st);
        float s0, s1;
        if (j < 32) { s0 = gram[i][j]; s1 = gram[i][j + 1]; }
        else        { s0 = gram[i][32]; s1 = gram[i + 1][i + 2]; }
        unsigned int pk = (unsigned int)f2bf(s0) | ((unsigned int)f2bf(s1) << 16);
        *(unsigned int*)(hb + p) = pk;
    }
}

// ---------------------------------------------------------------------------
// K4: MLP (unchanged).
// ---------------------------------------------------------------------------
__global__ __launch_bounds__(256) void k_mlp_mfma(
    const bf16_t* __restrict__ h, const bf16_t* __restrict__ Wt2,
    const float* __restrict__ b1, const float* __restrict__ gamma,
    const float* __restrict__ beta, const float* __restrict__ mean,
    const float* __restrict__ var, const float* __restrict__ outW,
    const float* __restrict__ outb, float* __restrict__ out)
{
    __shared__ float lds[2 * 16 * 65];
    __shared__ float red2[32];
    const int t = threadIdx.x, w = t >> 6, l = t & 63;
    const int lane15 = l & 15, quad = l >> 4;
    const int nhalf = w & 1, khalf = w >> 1;
    const int rowA = blockIdx.x * 16 + lane15;

    const bf16_t* ap = h + (size_t)rowA * 1600 + khalf * 800 + quad * 8;
    f32x4 acc[4] = {};

    #pragma unroll 2
    for (int it = 0; it < 25; it++) {
        short8 a = *(const short8*)(ap + it * 32);
        #pragma unroll
        for (int nt = 0; nt < 4; nt++) {
            int n = nhalf * 64 + nt * 16 + lane15;
            short8 bf = *(const short8*)(Wt2 + (size_t)n * 1600 + khalf * 800 + it * 32 + quad * 8);
            acc[nt] = __builtin_amdgcn_mfma_f32_16x16x32_bf16(a, bf, acc[nt], 0, 0, 0);
        }
    }

    if (khalf == 1) {
        #pragma unroll
        for (int nt = 0; nt < 4; nt++)
            #pragma unroll
            for (int i = 0; i < 4; i++)
                lds[nhalf * 1040 + (quad * 4 + i) * 65 + nt * 16 + lane15] = acc[nt][i];
    }
    __syncthreads();
    if (khalf == 0) {
        float pl[4] = { 0.f, 0.f, 0.f, 0.f };
        #pragma unroll
        for (int nt = 0; nt < 4; nt++) {
            int c = nhalf * 64 + nt * 16 + lane15;
            float sc = gamma[c] * rsqrtf(var[c] + 1e-3f);
            float sh = beta[c] - mean[c] * sc;
            float ow = outW[c], bb = b1[c];
            #pragma unroll
            for (int i = 0; i < 4; i++) {
                float v = acc[nt][i] + lds[nhalf * 1040 + (quad * 4 + i) * 65 + nt * 16 + lane15] + bb;
                v = fmaxf(v, 0.f);
                pl[i] += (v * sc + sh) * ow;
            }
        }
        #pragma unroll
        for (int m = 1; m < 16; m <<= 1)
            #pragma unroll
            for (int i = 0; i < 4; i++) pl[i] += __shfl_xor(pl[i], m);
        if (lane15 == 0) {
            #pragma unroll
            for (int i = 0; i < 4; i++) red2[(quad * 4 + i) * 2 + nhalf] = pl[i];
        }
    }
    __syncthreads();
    if (t < 16) {
        float s = red2[t * 2] + red2[t * 2 + 1] + outb[0];
        out[blockIdx.x * 16 + t] = 1.f / (1.f + __expf(-s));
    }
}

// ---------------------------------------------------------------------------
extern "C" void kernel_launch(void* const* d_in, const int* in_sizes, int n_in,
                              void* d_out, int out_size, void* d_ws, size_t ws_size,
                              hipStream_t stream) {
    const int*   sp       = (const int*)d_in[0];
    const float* dn       = (const float*)d_in[1];
    const float* gen_tab  = (const float*)d_in[2];
    const float* gen_W    = (const float*)d_in[3];
    const float* gen_b    = (const float*)d_in[4];
    const float* cls_tab  = (const float*)d_in[5];
    const float* cls_W    = (const float*)d_in[6];
    const float* cls_b    = (const float*)d_in[7];
    const float* conv_k0  = (const float*)d_in[8];
    const float* conv_b0  = (const float*)d_in[9];
    const float* fc_W0    = (const float*)d_in[10];
    const float* fc_b0    = (const float*)d_in[11];
    const float* conv_k1  = (const float*)d_in[12];
    const float* conv_b1  = (const float*)d_in[13];
    const float* fc_W1    = (const float*)d_in[14];
    const float* fc_b1    = (const float*)d_in[15];
    const float* mlp_W1   = (const float*)d_in[16];
    const float* mlp_b1   = (const float*)d_in[17];
    const float* bn_gamma = (const float*)d_in[18];
    const float* bn_beta  = (const float*)d_in[19];
    const float* bn_mean  = (const float*)d_in[20];
    const float* bn_var   = (const float*)d_in[21];
    const float* out_W    = (const float*)d_in[22];
    const float* out_b    = (const float*)d_in[23];
    float* out = (float*)d_out;

    char* ws = (char*)d_ws;
    bf16_t* pooled0 = (bf16_t*)(ws + 0);
    bf16_t* pooled1 = (bf16_t*)(ws + 54525952ULL);
    float*  p0      = (float*)(ws + 79691776ULL);
    float*  p1      = (float*)(ws + 92274688ULL);
    bf16_t* Wt0     = (bf16_t*)(ws + 104857600ULL);
    bf16_t* Wt1     = (bf16_t*)(ws + 105496576ULL);
    bf16_t* Wt2     = (bf16_t*)(ws + 105791488ULL);
    bf16_t* h       = (bf16_t*)(ws + 0);   // aliases pooled0 (consumed by fc before build_h)

    k_wtrans<<<dim3(52, 3), 256, 0, stream>>>(fc_W0, fc_W1, mlp_W1, Wt0, Wt1, Wt2);
    k_conv_fused<<<BATCH / 2, 256, 0, stream>>>(sp, dn, gen_tab, gen_W, gen_b,
                                                conv_k0, conv_b0, conv_k1, conv_b1,
                                                pooled0, pooled1);
    k_fc_mfma<<<dim3(BATCH / 64, 4, 2), 256, 0, stream>>>(pooled0, Wt0, p0, pooled1, Wt1, p1);
    k_build_h<<<BATCH / 4, 256, 0, stream>>>(sp, dn, cls_tab, cls_W, cls_b,
                                             p0, fc_b0, p1, fc_b1, h);
    k_mlp_mfma<<<BATCH / 16, 256, 0, stream>>>(h, Wt2, mlp_b1, bn_gamma, bn_beta,
                                               bn_mean, bn_var, out_W, out_b, out);
}

// Round 7
// 248.457 us; speedup vs baseline: 1.6482x; 1.1574x over previous
//
#include <hip/hip_runtime.h>
#include <hip/hip_bf16.h>
#include <math.h>

#define BATCH 8192

typedef unsigned short bf16_t;
typedef _Float16 f16_t;
typedef __attribute__((ext_vector_type(2))) _Float16 h2_t;
typedef __attribute__((ext_vector_type(8))) short short8;
typedef __attribute__((ext_vector_type(4))) float f32x4;

union U32H2 { unsigned int u; h2_t h; };

__device__ __forceinline__ float bf2f(bf16_t u) {
    union { unsigned int i; float f; } v; v.i = ((unsigned int)u) << 16; return v.f;
}
__device__ __forceinline__ bf16_t f2bf(float f) {
    union { float f; unsigned int i; } v; v.f = f;
    unsigned int x = v.i;
    unsigned int r = (x + 0x7FFFu + ((x >> 16) & 1u)) >> 16;   // RNE
    return (bf16_t)r;
}
// tanh(x) = sign(x) * (1 - 2/(exp(2|x|)+1)); err ~1e-6
__device__ __forceinline__ float fast_tanh(float x) {
    float ax = fabsf(x);
    float e = __expf(ax + ax);
    float t = 1.0f - 2.0f * __builtin_amdgcn_rcpf(e + 1.0f);
    return copysignf(t, x);
}

// ---------------------------------------------------------------------------
// Packed operand layouts (MFMA fragment-native):
//  B (weights):  elem P = ((git*NT + nt)*64 + lane)*8 + e
//                holds W[n = nt*16 + (lane&15)][k = git*32 + (lane>>4)*8 + e]
//  A (acts):     elem = ((rb*(K/8) + (k>>3))*128) + (row&15)*8 + (k&7),
//                rb = row>>4. A wave's 16-row x 32-k fragment load is 1 KB
//                contiguous.
// ---------------------------------------------------------------------------

// K0: pack weights into B-fragment order.
__device__ __forceinline__ void wpack_one(
    const float* __restrict__ src, bf16_t* __restrict__ dst,
    int P, int N, int NT, int Ksrc)
{
    int e = P & 7, lane = (P >> 3) & 63, idx = P >> 9;
    int nt = idx % NT, git = idx / NT;
    int n = nt * 16 + (lane & 15);
    int k = git * 32 + (lane >> 4) * 8 + e;
    dst[P] = (k < Ksrc) ? f2bf(src[(size_t)k * N + n]) : (bf16_t)0;
}

__global__ __launch_bounds__(256) void k_wpack(
    const float* __restrict__ W0, const float* __restrict__ W1, const float* __restrict__ W2,
    bf16_t* __restrict__ Wt0, bf16_t* __restrict__ Wt1, bf16_t* __restrict__ Wt2)
{
    const int m = blockIdx.y;
    const int P = blockIdx.x * 256 + threadIdx.x;
    if (m == 0)      { if (P < 319488) wpack_one(W0, Wt0, P, 96, 6, 3328); }
    else if (m == 1) { if (P < 147456) wpack_one(W1, Wt1, P, 96, 6, 1536); }
    else             { if (P < 204800) wpack_one(W2, Wt2, P, 128, 8, 1584); }
}

// ---------------------------------------------------------------------------
// K1: fused conv path, 2 samples/block; pooled0/pooled1 written in packed
//     A-fragment layout.
// ---------------------------------------------------------------------------
__global__ __launch_bounds__(256) void k_conv_fused(
    const int* __restrict__ sp, const float* __restrict__ dn,
    const float* __restrict__ gen_table, const float* __restrict__ gen_W, const float* __restrict__ gen_b,
    const float* __restrict__ k0, const float* __restrict__ b0,
    const float* __restrict__ k1, const float* __restrict__ b1,
    bf16_t* __restrict__ pooled0, bf16_t* __restrict__ pooled1)
{
    __shared__ float embGt[2][32][28];             // [s][w][h], h=0..26
    __shared__ unsigned int x0[2 * 13 * 32 * 4];   // f16-pair words [s][hp][w][q]
    __shared__ float k0s[56], k1s[448], b0s[8], b1s[8];
    __shared__ int ids[52];
    __shared__ float dloc[26];
    const int t = threadIdx.x;
    const int half = t >> 7, tt = t & 127;
    const int b = blockIdx.x * 2 + half;

    if (tt < 26) ids[half * 26 + tt] = sp[b * 26 + tt];
    if (tt >= 32 && tt < 45) dloc[half * 13 + tt - 32] = dn[b * 13 + (tt - 32)];
    if (t < 56) k0s[t] = k0[t];
    if (t >= 64 && t < 72) b0s[t - 64] = b0[t - 64];
    if (t >= 72 && t < 80) b1s[t - 72] = b1[t - 72];
    for (int i = t; i < 448; i += 256) k1s[i] = k1[i];
    __syncthreads();

    for (int i = tt; i < 416; i += 128) {
        int s_ = i >> 4, d = (i & 15) * 2;
        float2 v = *(const float2*)(gen_table + (size_t)ids[half * 26 + s_] * 32 + d);
        embGt[half][d][s_] = v.x;
        embGt[half][d + 1][s_] = v.y;
    }
    if (tt < 32) {
        float a = gen_b[tt];
        #pragma unroll
        for (int k = 0; k < 13; k++) a += dloc[half * 13 + k] * gen_W[k * 32 + tt];
        embGt[half][tt][26] = a;
    }
    __syncthreads();

    // packed bases for this sample
    bf16_t* p0base = pooled0 + ((size_t)(b >> 4) * 416) * 128 + (b & 15) * 8;

    // ---- conv0 + pool + tanh (27 -> 13)
    {
        const int w = tt >> 2, f0 = (tt & 3) * 2;
        const float* xp = &embGt[half][w][0];
        float xr[28];
        #pragma unroll
        for (int q = 0; q < 7; q++) {
            float4 v = *(const float4*)(xp + 4 * q);
            xr[4 * q] = v.x; xr[4 * q + 1] = v.y; xr[4 * q + 2] = v.z; xr[4 * q + 3] = v.w;
        }
        float k0r[7][2];
        #pragma unroll
        for (int tap = 0; tap < 7; tap++) {
            k0r[tap][0] = k0s[tap * 8 + f0];
            k0r[tap][1] = k0s[tap * 8 + f0 + 1];
        }
        const float b00 = b0s[f0], b01 = b0s[f0 + 1];
        #pragma unroll
        for (int hp = 0; hp < 13; hp++) {
            float p00 = b00, p01 = b01, p10 = b00, p11 = b01;
            #pragma unroll
            for (int tap = 0; tap < 7; tap++) {
                const int h0 = 2 * hp + tap - 3;
                if (h0 >= 0 && h0 < 27) {
                    p00 += xr[h0] * k0r[tap][0];
                    p01 += xr[h0] * k0r[tap][1];
                }
                const int h1 = 2 * hp + 1 + tap - 3;
                if (h1 >= 0 && h1 < 27) {
                    p10 += xr[h1] * k0r[tap][0];
                    p11 += xr[h1] * k0r[tap][1];
                }
            }
            float m0 = fast_tanh(fmaxf(p00, p10));
            float m1 = fast_tanh(fmaxf(p01, p11));
            unsigned int pk = (unsigned int)f2bf(m0) | ((unsigned int)f2bf(m1) << 16);
            *(unsigned int*)(p0base + (hp * 32 + w) * 128 + f0) = pk;
            U32H2 hx; hx.h = h2_t{(f16_t)m0, (f16_t)m1};
            x0[half * 1664 + hp * 128 + w * 4 + (tt & 3)] = hx.u;
        }
    }
    __syncthreads();

    // ---- conv1 + pool + tanh (13 -> 6), packed f16
    {
        const int w1 = t >> 3, fo = t & 7;
        h2_t kh[7][4];
        #pragma unroll
        for (int tap = 0; tap < 7; tap++)
            #pragma unroll
            for (int q = 0; q < 4; q++)
                kh[tap][q] = h2_t{(f16_t)k1s[tap * 64 + (2 * q) * 8 + fo],
                                  (f16_t)k1s[tap * 64 + (2 * q + 1) * 8 + fo]};
        const f16_t bbh = (f16_t)b1s[fo];

        #pragma unroll
        for (int s = 0; s < 2; s++) {
            h2_t acc[12];
            #pragma unroll
            for (int r = 0; r < 12; r++) acc[r] = h2_t{bbh, (f16_t)0.f};
            #pragma unroll
            for (int hh = 0; hh < 13; hh++) {
                uint4 v = *(const uint4*)&x0[s * 1664 + hh * 128 + w1 * 4];
                U32H2 c0, c1, c2, c3;
                c0.u = v.x; c1.u = v.y; c2.u = v.z; c3.u = v.w;
                h2_t x2[4] = { c0.h, c1.h, c2.h, c3.h };
                #pragma unroll
                for (int tap = 0; tap < 7; tap++) {
                    const int r = hh + 3 - tap;
                    if (r >= 0 && r < 12) {
                        #pragma unroll
                        for (int q = 0; q < 4; q++) acc[r] += x2[q] * kh[tap][q];
                    }
                }
            }
            const int bs = blockIdx.x * 2 + s;
            bf16_t* p1base = pooled1 + ((size_t)(bs >> 4) * 192) * 128 + (bs & 15) * 8;
            #pragma unroll
            for (int hp = 0; hp < 6; hp++) {
                float a0 = (float)acc[2 * hp][0] + (float)acc[2 * hp][1];
                float a1 = (float)acc[2 * hp + 1][0] + (float)acc[2 * hp + 1][1];
                float m = fast_tanh(fmaxf(a0, a1));
                p1base[(hp * 32 + w1) * 128 + fo] = f2bf(m);
            }
        }
    }
}

// ---------------------------------------------------------------------------
// K2: both fc GEMMs, packed operands, fully coalesced fragment loads.
// grid (M/64, splitK=4, 2). wave = 16 rows x 96 cols.
// ---------------------------------------------------------------------------
__global__ __launch_bounds__(256) void k_fc_mfma(
    const bf16_t* __restrict__ A0, const bf16_t* __restrict__ Wt0, float* __restrict__ P0,
    const bf16_t* __restrict__ A1, const bf16_t* __restrict__ Wt1, float* __restrict__ P1)
{
    const int which = blockIdx.z;
    const bf16_t* A  = which ? A1 : A0;
    const bf16_t* Wt = which ? Wt1 : Wt0;
    float* P = (which ? P1 : P0) + (size_t)blockIdx.y * (BATCH * 96);
    const int K = which ? 1536 : 3328;
    const int iters = which ? 12 : 26;

    const int t = threadIdx.x, w = t >> 6, l = t & 63;
    const int lane15 = l & 15, quad = l >> 4;
    const int rb = blockIdx.x * 4 + w;
    const int kb = blockIdx.y * (K >> 2);

    const bf16_t* ap = A + ((size_t)rb * (K >> 3) + (kb >> 3) + quad) * 128 + lane15 * 8;
    const bf16_t* bp = Wt + (size_t)(kb >> 5) * 3072 + l * 8;   // NT=6 -> 6*512
    f32x4 acc[6] = {};

    #pragma unroll 2
    for (int it = 0; it < iters; it++) {
        short8 a = *(const short8*)(ap + it * 512);
        #pragma unroll
        for (int nt = 0; nt < 6; nt++) {
            short8 bf = *(const short8*)(bp + it * 3072 + nt * 512);
            acc[nt] = __builtin_amdgcn_mfma_f32_16x16x32_bf16(a, bf, acc[nt], 0, 0, 0);
        }
    }
    const int baser = blockIdx.x * 64 + w * 16 + quad * 4;
    #pragma unroll
    for (int nt = 0; nt < 6; nt++)
        #pragma unroll
        for (int i = 0; i < 4; i++)
            P[(size_t)(baser + i) * 96 + nt * 16 + lane15] = acc[nt][i];
}

// ---------------------------------------------------------------------------
// K3: build h (packed A-fragment layout, row-block16 x 200 k-chunks).
// One sample per wave; gram via 3 MFMAs.
// ---------------------------------------------------------------------------
__global__ __launch_bounds__(256) void k_build_h(
    const int* __restrict__ sp, const float* __restrict__ dn,
    const float* __restrict__ cls_table, const float* __restrict__ cls_W, const float* __restrict__ cls_b,
    const float* __restrict__ p0, const float* __restrict__ fb0,
    const float* __restrict__ p1, const float* __restrict__ fb1,
    bf16_t* __restrict__ h)
{
    __shared__ bf16_t augs[4][33][40];
    __shared__ float grams[4][32][34];
    const int t = threadIdx.x, wv = t >> 6, l = t & 63;
    const int b = blockIdx.x * 4 + wv;
    bf16_t (*aug)[40] = augs[wv];
    float (*gram)[34] = grams[wv];

    const int myid = (l < 26) ? sp[b * 26 + l] : 0;

    for (int i = l; i < 416; i += 64) {
        int s_ = i >> 4, d = (i & 15) * 2;
        int id = __shfl(myid, s_);
        float2 v = *(const float2*)(cls_table + (size_t)id * 32 + d);
        unsigned int pk = (unsigned int)f2bf(v.x) | ((unsigned int)f2bf(v.y) << 16);
        *(unsigned int*)&aug[s_][d] = pk;
    }
    if (l < 32) {
        float a = cls_b[l];
        #pragma unroll
        for (int k = 0; k < 13; k++) a += dn[b * 13 + k] * cls_W[k * 32 + l];
        aug[26][l] = f2bf(a);
    }
    for (int i = l; i < 192; i += 64) {
        int n = 27 + (i >> 5), d = i & 31;
        float s;
        if (i < 96) {
            size_t o = (size_t)b * 96 + i;
            s = p0[o] + p0[o + 786432] + p0[o + 2 * 786432] + p0[o + 3 * 786432] + fb0[i];
        } else {
            int j = i - 96; size_t o = (size_t)b * 96 + j;
            s = p1[o] + p1[o + 786432] + p1[o + 2 * 786432] + p1[o + 3 * 786432] + fb1[j];
        }
        aug[n][d] = f2bf(fast_tanh(s));
    }

    const int m16 = l & 15, quad = l >> 4;
    short8 a0 = *(const short8*)&aug[m16][quad * 8];
    short8 a1 = *(const short8*)&aug[16 + m16][quad * 8];
    f32x4 c00 = {}, c01 = {}, c11 = {};
    c00 = __builtin_amdgcn_mfma_f32_16x16x32_bf16(a0, a0, c00, 0, 0, 0);
    c01 = __builtin_amdgcn_mfma_f32_16x16x32_bf16(a0, a1, c01, 0, 0, 0);
    c11 = __builtin_amdgcn_mfma_f32_16x16x32_bf16(a1, a1, c11, 0, 0, 0);
    #pragma unroll
    for (int i = 0; i < 4; i++) {
        gram[quad * 4 + i][m16] = c00[i];
        gram[quad * 4 + i][16 + m16] = c01[i];
        gram[16 + quad * 4 + i][16 + m16] = c11[i];
    }
    if (l < 32) {
        float s = 0.f;
        #pragma unroll
        for (int kk = 0; kk < 16; kk++) {
            unsigned int x = *(const unsigned int*)&aug[l][2 * kk];
            unsigned int y = *(const unsigned int*)&aug[32][2 * kk];
            s += bf2f((bf16_t)(x & 0xFFFFu)) * bf2f((bf16_t)(y & 0xFFFFu));
            s += bf2f((bf16_t)(x >> 16)) * bf2f((bf16_t)(y >> 16));
        }
        gram[l][32] = s;
    }

    // packed h writes: base for this sample
    bf16_t* hbp = h + ((size_t)(b >> 4) * 200) * 128 + (b & 15) * 8;
    // aug flat copy: k = 528 + 2*idx
    for (int idx = l; idx < 528; idx += 64) {
        int k = 528 + 2 * idx;
        *(unsigned int*)(hbp + (k >> 3) * 128 + (k & 7)) = *(const unsigned int*)&aug[idx >> 4][(idx & 15) * 2];
    }
    if (l < 8) {
        int k = 1584 + 2 * l;
        *(unsigned int*)(hbp + (k >> 3) * 128 + (k & 7)) = 0u;
    }
    for (int pp = l; pp < 264; pp += 64) {
        int p = 2 * pp;
        int i = (int)((65.0f - sqrtf(4225.0f - 8.0f * (float)p)) * 0.5f);
        int st = (i * (65 - i)) >> 1;
        if (st > p) { i--; st = (i * (65 - i)) >> 1; }
        else { int st2 = ((i + 1) * (64 - i)) >> 1; if (st2 <= p) { i++; st = st2; } }
        int j = i + 1 + (p - st);
        float s0, s1;
        if (j < 32) { s0 = gram[i][j]; s1 = gram[i][j + 1]; }
        else        { s0 = gram[i][32]; s1 = gram[i + 1][i + 2]; }
        unsigned int pk = (unsigned int)f2bf(s0) | ((unsigned int)f2bf(s1) << 16);
        *(unsigned int*)(hbp + (p >> 3) * 128 + (p & 7)) = pk;
    }
}

// ---------------------------------------------------------------------------
// K4: MLP, packed operands. Block = 16 rows (= one packed row-block).
// ---------------------------------------------------------------------------
__global__ __launch_bounds__(256) void k_mlp_mfma(
    const bf16_t* __restrict__ h, const bf16_t* __restrict__ Wt2,
    const float* __restrict__ b1, const float* __restrict__ gamma,
    const float* __restrict__ beta, const float* __restrict__ mean,
    const float* __restrict__ var, const float* __restrict__ outW,
    const float* __restrict__ outb, float* __restrict__ out)
{
    __shared__ float lds[2 * 16 * 65];
    __shared__ float red2[32];
    const int t = threadIdx.x, w = t >> 6, l = t & 63;
    const int lane15 = l & 15, quad = l >> 4;
    const int nhalf = w & 1, khalf = w >> 1;

    const bf16_t* ap = h + ((size_t)blockIdx.x * 200 + khalf * 100 + quad) * 128 + lane15 * 8;
    const bf16_t* bp = Wt2 + ((size_t)khalf * 25 * 8 + nhalf * 4) * 512 + l * 8;
    f32x4 acc[4] = {};

    #pragma unroll 2
    for (int it = 0; it < 25; it++) {
        short8 a = *(const short8*)(ap + it * 512);
        #pragma unroll
        for (int nt = 0; nt < 4; nt++) {
            short8 bf = *(const short8*)(bp + it * 4096 + nt * 512);
            acc[nt] = __builtin_amdgcn_mfma_f32_16x16x32_bf16(a, bf, acc[nt], 0, 0, 0);
        }
    }

    if (khalf == 1) {
        #pragma unroll
        for (int nt = 0; nt < 4; nt++)
            #pragma unroll
            for (int i = 0; i < 4; i++)
                lds[nhalf * 1040 + (quad * 4 + i) * 65 + nt * 16 + lane15] = acc[nt][i];
    }
    __syncthreads();
    if (khalf == 0) {
        float pl[4] = { 0.f, 0.f, 0.f, 0.f };
        #pragma unroll
        for (int nt = 0; nt < 4; nt++) {
            int c = nhalf * 64 + nt * 16 + lane15;
            float sc = gamma[c] * rsqrtf(var[c] + 1e-3f);
            float sh = beta[c] - mean[c] * sc;
            float ow = outW[c], bb = b1[c];
            #pragma unroll
            for (int i = 0; i < 4; i++) {
                float v = acc[nt][i] + lds[nhalf * 1040 + (quad * 4 + i) * 65 + nt * 16 + lane15] + bb;
                v = fmaxf(v, 0.f);
                pl[i] += (v * sc + sh) * ow;
            }
        }
        #pragma unroll
        for (int m = 1; m < 16; m <<= 1)
            #pragma unroll
            for (int i = 0; i < 4; i++) pl[i] += __shfl_xor(pl[i], m);
        if (lane15 == 0) {
            #pragma unroll
            for (int i = 0; i < 4; i++) red2[(quad * 4 + i) * 2 + nhalf] = pl[i];
        }
    }
    __syncthreads();
    if (t < 16) {
        float s = red2[t * 2] + red2[t * 2 + 1] + outb[0];
        out[blockIdx.x * 16 + t] = 1.f / (1.f + __expf(-s));
    }
}

// ---------------------------------------------------------------------------
extern "C" void kernel_launch(void* const* d_in, const int* in_sizes, int n_in,
                              void* d_out, int out_size, void* d_ws, size_t ws_size,
                              hipStream_t stream) {
    const int*   sp       = (const int*)d_in[0];
    const float* dn       = (const float*)d_in[1];
    const float* gen_tab  = (const float*)d_in[2];
    const float* gen_W    = (const float*)d_in[3];
    const float* gen_b    = (const float*)d_in[4];
    const float* cls_tab  = (const float*)d_in[5];
    const float* cls_W    = (const float*)d_in[6];
    const float* cls_b    = (const float*)d_in[7];
    const float* conv_k0  = (const float*)d_in[8];
    const float* conv_b0  = (const float*)d_in[9];
    const float* fc_W0    = (const float*)d_in[10];
    const float* fc_b0    = (const float*)d_in[11];
    const float* conv_k1  = (const float*)d_in[12];
    const float* conv_b1  = (const float*)d_in[13];
    const float* fc_W1    = (const float*)d_in[14];
    const float* fc_b1    = (const float*)d_in[15];
    const float* mlp_W1   = (const float*)d_in[16];
    const float* mlp_b1   = (const float*)d_in[17];
    const float* bn_gamma = (const float*)d_in[18];
    const float* bn_beta  = (const float*)d_in[19];
    const float* bn_mean  = (const float*)d_in[20];
    const float* bn_var   = (const float*)d_in[21];
    const float* out_W    = (const float*)d_in[22];
    const float* out_b    = (const float*)d_in[23];
    float* out = (float*)d_out;

    char* ws = (char*)d_ws;
    bf16_t* pooled0 = (bf16_t*)(ws + 0);
    bf16_t* pooled1 = (bf16_t*)(ws + 54525952ULL);
    float*  p0      = (float*)(ws + 79691776ULL);
    float*  p1      = (float*)(ws + 92274688ULL);
    bf16_t* Wt0     = (bf16_t*)(ws + 104857600ULL);
    bf16_t* Wt1     = (bf16_t*)(ws + 105496576ULL);
    bf16_t* Wt2     = (bf16_t*)(ws + 105791488ULL);
    bf16_t* h       = (bf16_t*)(ws + 0);   // aliases pooled0 (consumed by fc before build_h)

    k_wpack<<<dim3(1248, 3), 256, 0, stream>>>(fc_W0, fc_W1, mlp_W1, Wt0, Wt1, Wt2);
    k_conv_fused<<<BATCH / 2, 256, 0, stream>>>(sp, dn, gen_tab, gen_W, gen_b,
                                                conv_k0, conv_b0, conv_k1, conv_b1,
                                                pooled0, pooled1);
    k_fc_mfma<<<dim3(BATCH / 64, 4, 2), 256, 0, stream>>>(pooled0, Wt0, p0, pooled1, Wt1, p1);
    k_build_h<<<BATCH / 4, 256, 0, stream>>>(sp, dn, cls_tab, cls_W, cls_b,
                                             p0, fc_b0, p1, fc_b1, h);
    k_mlp_mfma<<<BATCH / 16, 256, 0, stream>>>(h, Wt2, mlp_b1, bn_gamma, bn_beta,
                                               bn_mean, bn_var, out_W, out_b, out);
}

// Round 8
// 241.563 us; speedup vs baseline: 1.6952x; 1.0285x over previous
//
#include <hip/hip_runtime.h>
#include <hip/hip_bf16.h>
#include <math.h>

#define BATCH 8192

typedef unsigned short bf16_t;
typedef _Float16 f16_t;
typedef __attribute__((ext_vector_type(2))) _Float16 h2_t;
typedef __attribute__((ext_vector_type(8))) short short8;
typedef __attribute__((ext_vector_type(4))) float f32x4;

union U32H2 { unsigned int u; h2_t h; };

__device__ __forceinline__ float bf2f(bf16_t u) {
    union { unsigned int i; float f; } v; v.i = ((unsigned int)u) << 16; return v.f;
}
__device__ __forceinline__ bf16_t f2bf(float f) {
    union { float f; unsigned int i; } v; v.f = f;
    unsigned int x = v.i;
    unsigned int r = (x + 0x7FFFu + ((x >> 16) & 1u)) >> 16;   // RNE
    return (bf16_t)r;
}
// tanh(x) = sign(x) * (1 - 2/(exp(2|x|)+1)); err ~1e-6
__device__ __forceinline__ float fast_tanh(float x) {
    float ax = fabsf(x);
    float e = __expf(ax + ax);
    float t = 1.0f - 2.0f * __builtin_amdgcn_rcpf(e + 1.0f);
    return copysignf(t, x);
}
__device__ __forceinline__ h2_t hmax2(h2_t a, h2_t b) {
    h2_t r;
    r[0] = a[0] > b[0] ? a[0] : b[0];
    r[1] = a[1] > b[1] ? a[1] : b[1];
    return r;
}

// ---------------------------------------------------------------------------
// Packed operand layouts (MFMA fragment-native):
//  B (weights): elem P = ((git*NT + nt)*64 + lane)*8 + e
//  A (acts):    elem = ((rb*(K/8) + (k>>3))*128) + (row&15)*8 + (k&7)
// ---------------------------------------------------------------------------
__device__ __forceinline__ void wpack_one(
    const float* __restrict__ src, bf16_t* __restrict__ dst,
    int P, int N, int NT, int Ksrc)
{
    int e = P & 7, lane = (P >> 3) & 63, idx = P >> 9;
    int nt = idx % NT, git = idx / NT;
    int n = nt * 16 + (lane & 15);
    int k = git * 32 + (lane >> 4) * 8 + e;
    dst[P] = (k < Ksrc) ? f2bf(src[(size_t)k * N + n]) : (bf16_t)0;
}

__global__ __launch_bounds__(256) void k_wpack(
    const float* __restrict__ W0, const float* __restrict__ W1, const float* __restrict__ W2,
    bf16_t* __restrict__ Wt0, bf16_t* __restrict__ Wt1, bf16_t* __restrict__ Wt2)
{
    const int m = blockIdx.y;
    const int P = blockIdx.x * 256 + threadIdx.x;
    if (m == 0)      { if (P < 319488) wpack_one(W0, Wt0, P, 96, 6, 3328); }
    else if (m == 1) { if (P < 147456) wpack_one(W1, Wt1, P, 96, 6, 1536); }
    else             { if (P < 204800) wpack_one(W2, Wt2, P, 128, 8, 1584); }
}

// ---------------------------------------------------------------------------
// K1: fused conv path, 2 samples/block.
// conv0: position-per-thread (s,hp,w) computes all 8 f via packed f16 math,
//        one uint4 store to packed pooled0 + one uint4 LDS store (x0, f16).
// conv1: thread=(w,fo) packed-f16 accumulation; outputs staged in LDS,
//        flushed as uint4 to packed pooled1.
// ---------------------------------------------------------------------------
__global__ __launch_bounds__(256) void k_conv_fused(
    const int* __restrict__ sp, const float* __restrict__ dn,
    const float* __restrict__ gen_table, const float* __restrict__ gen_W, const float* __restrict__ gen_b,
    const float* __restrict__ k0, const float* __restrict__ b0,
    const float* __restrict__ k1, const float* __restrict__ b1,
    bf16_t* __restrict__ pooled0, bf16_t* __restrict__ pooled1)
{
    __shared__ float embGt[2][32][28];             // [s][w][h], h=0..26, f32
    __shared__ unsigned int x0[2 * 13 * 32 * 4];   // f16-pair words [s][hp][w][q]
    __shared__ bf16_t stage1[2][192][8];           // conv1 outputs, chunk-major
    __shared__ float k0s[56], k1s[448], b0s[8], b1s[8];
    __shared__ int ids[52];
    __shared__ float dloc[26];
    const int t = threadIdx.x;
    const int half = t >> 7, tt = t & 127;
    const int b = blockIdx.x * 2 + half;

    if (tt < 26) ids[half * 26 + tt] = sp[b * 26 + tt];
    if (tt >= 32 && tt < 45) dloc[half * 13 + tt - 32] = dn[b * 13 + (tt - 32)];
    if (t < 56) k0s[t] = k0[t];
    if (t >= 64 && t < 72) b0s[t - 64] = b0[t - 64];
    if (t >= 72 && t < 80) b1s[t - 72] = b1[t - 72];
    for (int i = t; i < 448; i += 256) k1s[i] = k1[i];
    __syncthreads();

    for (int i = tt; i < 416; i += 128) {
        int s_ = i >> 4, d = (i & 15) * 2;
        float2 v = *(const float2*)(gen_table + (size_t)ids[half * 26 + s_] * 32 + d);
        embGt[half][d][s_] = v.x;
        embGt[half][d + 1][s_] = v.y;
    }
    if (tt < 32) {
        float a = gen_b[tt];
        #pragma unroll
        for (int k = 0; k < 13; k++) a += dloc[half * 13 + k] * gen_W[k * 32 + tt];
        embGt[half][tt][26] = a;
    }
    __syncthreads();

    // ---- conv0 + pool + tanh: 832 positions = 2 samples x 13 hp x 32 w
    {
        h2_t k0h[7][4], b0h[4];
        #pragma unroll
        for (int tap = 0; tap < 7; tap++)
            #pragma unroll
            for (int q = 0; q < 4; q++)
                k0h[tap][q] = h2_t{(f16_t)k0s[tap * 8 + 2 * q], (f16_t)k0s[tap * 8 + 2 * q + 1]};
        #pragma unroll
        for (int q = 0; q < 4; q++)
            b0h[q] = h2_t{(f16_t)b0s[2 * q], (f16_t)b0s[2 * q + 1]};

        #pragma unroll
        for (int pi = 0; pi < 4; pi++) {
            int pos = t + pi * 256;
            if (pos < 832) {
                int s = (pos >= 416) ? 1 : 0;
                int q_ = pos - s * 416;
                int hp = q_ >> 5, w = q_ & 31;
                int bb = blockIdx.x * 2 + s;
                const float* xp = &embGt[s][w][0];
                f16_t xs[8];
                #pragma unroll
                for (int j = 0; j < 8; j++) {
                    int hh = 2 * hp - 3 + j;
                    float v = (hh >= 0 && hh < 27) ? xp[hh] : 0.f;
                    xs[j] = (f16_t)v;
                }
                h2_t acc0[4], acc1[4];
                #pragma unroll
                for (int q = 0; q < 4; q++) { acc0[q] = b0h[q]; acc1[q] = b0h[q]; }
                #pragma unroll
                for (int tap = 0; tap < 7; tap++) {
                    h2_t s0 = h2_t{xs[tap], xs[tap]};
                    h2_t s1 = h2_t{xs[tap + 1], xs[tap + 1]};
                    #pragma unroll
                    for (int q = 0; q < 4; q++) {
                        acc0[q] += s0 * k0h[tap][q];
                        acc1[q] += s1 * k0h[tap][q];
                    }
                }
                unsigned int outw[4], xw[4];
                #pragma unroll
                for (int q = 0; q < 4; q++) {
                    h2_t mx = hmax2(acc0[q], acc1[q]);
                    float t0 = fast_tanh((float)mx[0]);
                    float t1 = fast_tanh((float)mx[1]);
                    outw[q] = (unsigned int)f2bf(t0) | ((unsigned int)f2bf(t1) << 16);
                    U32H2 hx; hx.h = h2_t{(f16_t)t0, (f16_t)t1};
                    xw[q] = hx.u;
                }
                uint4 ov = make_uint4(outw[0], outw[1], outw[2], outw[3]);
                *(uint4*)(pooled0 + (((size_t)(bb >> 4) * 416 + hp * 32 + w) * 128 + (bb & 15) * 8)) = ov;
                uint4 xv = make_uint4(xw[0], xw[1], xw[2], xw[3]);
                *(uint4*)&x0[s * 1664 + hp * 128 + w * 4] = xv;
            }
        }
    }
    __syncthreads();

    // ---- conv1 + pool + tanh (13 -> 6), packed f16; stage outputs in LDS
    {
        const int w1 = t >> 3, fo = t & 7;
        h2_t kh[7][4];
        #pragma unroll
        for (int tap = 0; tap < 7; tap++)
            #pragma unroll
            for (int q = 0; q < 4; q++)
                kh[tap][q] = h2_t{(f16_t)k1s[tap * 64 + (2 * q) * 8 + fo],
                                  (f16_t)k1s[tap * 64 + (2 * q + 1) * 8 + fo]};
        const f16_t bbh = (f16_t)b1s[fo];

        #pragma unroll
        for (int s = 0; s < 2; s++) {
            h2_t acc[12];
            #pragma unroll
            for (int r = 0; r < 12; r++) acc[r] = h2_t{bbh, (f16_t)0.f};
            #pragma unroll
            for (int hh = 0; hh < 13; hh++) {
                uint4 v = *(const uint4*)&x0[s * 1664 + hh * 128 + w1 * 4];
                U32H2 c0, c1, c2, c3;
                c0.u = v.x; c1.u = v.y; c2.u = v.z; c3.u = v.w;
                h2_t x2[4] = { c0.h, c1.h, c2.h, c3.h };
                #pragma unroll
                for (int tap = 0; tap < 7; tap++) {
                    const int r = hh + 3 - tap;
                    if (r >= 0 && r < 12) {
                        #pragma unroll
                        for (int q = 0; q < 4; q++) acc[r] += x2[q] * kh[tap][q];
                    }
                }
            }
            #pragma unroll
            for (int hp = 0; hp < 6; hp++) {
                float a0 = (float)acc[2 * hp][0] + (float)acc[2 * hp][1];
                float a1 = (float)acc[2 * hp + 1][0] + (float)acc[2 * hp + 1][1];
                float m = fast_tanh(fmaxf(a0, a1));
                stage1[s][hp * 32 + w1][fo] = f2bf(m);
            }
        }
    }
    __syncthreads();
    // flush conv1 outputs: 384 chunks of 16B
    {
        #pragma unroll
        for (int i = t; i < 384; i += 256) {
            int s = (i >= 192) ? 1 : 0;
            int c = i - s * 192;
            int bs = blockIdx.x * 2 + s;
            uint4 v = *(const uint4*)&stage1[s][c][0];
            *(uint4*)(pooled1 + (((size_t)(bs >> 4) * 192 + c) * 128 + (bs & 15) * 8)) = v;
        }
    }
}

// ---------------------------------------------------------------------------
// K2: both fc GEMMs, packed operands (unchanged).
// ---------------------------------------------------------------------------
__global__ __launch_bounds__(256) void k_fc_mfma(
    const bf16_t* __restrict__ A0, const bf16_t* __restrict__ Wt0, float* __restrict__ P0,
    const bf16_t* __restrict__ A1, const bf16_t* __restrict__ Wt1, float* __restrict__ P1)
{
    const int which = blockIdx.z;
    const bf16_t* A  = which ? A1 : A0;
    const bf16_t* Wt = which ? Wt1 : Wt0;
    float* P = (which ? P1 : P0) + (size_t)blockIdx.y * (BATCH * 96);
    const int K = which ? 1536 : 3328;
    const int iters = which ? 12 : 26;

    const int t = threadIdx.x, w = t >> 6, l = t & 63;
    const int lane15 = l & 15, quad = l >> 4;
    const int rb = blockIdx.x * 4 + w;
    const int kb = blockIdx.y * (K >> 2);

    const bf16_t* ap = A + ((size_t)rb * (K >> 3) + (kb >> 3) + quad) * 128 + lane15 * 8;
    const bf16_t* bp = Wt + (size_t)(kb >> 5) * 3072 + l * 8;
    f32x4 acc[6] = {};

    #pragma unroll 2
    for (int it = 0; it < iters; it++) {
        short8 a = *(const short8*)(ap + it * 512);
        #pragma unroll
        for (int nt = 0; nt < 6; nt++) {
            short8 bf = *(const short8*)(bp + it * 3072 + nt * 512);
            acc[nt] = __builtin_amdgcn_mfma_f32_16x16x32_bf16(a, bf, acc[nt], 0, 0, 0);
        }
    }
    const int baser = blockIdx.x * 64 + w * 16 + quad * 4;
    #pragma unroll
    for (int nt = 0; nt < 6; nt++)
        #pragma unroll
        for (int i = 0; i < 4; i++)
            P[(size_t)(baser + i) * 96 + nt * 16 + lane15] = acc[nt][i];
}

// ---------------------------------------------------------------------------
// K3: build h. One sample per wave; gram via 3 MFMAs; h row staged in LDS
// then flushed as uint4 chunks (packed A layout).
// ---------------------------------------------------------------------------
__global__ __launch_bounds__(256) void k_build_h(
    const int* __restrict__ sp, const float* __restrict__ dn,
    const float* __restrict__ cls_table, const float* __restrict__ cls_W, const float* __restrict__ cls_b,
    const float* __restrict__ p0, const float* __restrict__ fb0,
    const float* __restrict__ p1, const float* __restrict__ fb1,
    bf16_t* __restrict__ h)
{
    __shared__ bf16_t augs[4][33][40];
    __shared__ float grams[4][32][34];
    __shared__ bf16_t hrows[4][1600];
    const int t = threadIdx.x, wv = t >> 6, l = t & 63;
    const int b = blockIdx.x * 4 + wv;
    bf16_t (*aug)[40] = augs[wv];
    float (*gram)[34] = grams[wv];
    bf16_t* hrow = hrows[wv];

    const int myid = (l < 26) ? sp[b * 26 + l] : 0;

    for (int i = l; i < 416; i += 64) {
        int s_ = i >> 4, d = (i & 15) * 2;
        int id = __shfl(myid, s_);
        float2 v = *(const float2*)(cls_table + (size_t)id * 32 + d);
        unsigned int pk = (unsigned int)f2bf(v.x) | ((unsigned int)f2bf(v.y) << 16);
        *(unsigned int*)&aug[s_][d] = pk;
    }
    if (l < 32) {
        float a = cls_b[l];
        #pragma unroll
        for (int k = 0; k < 13; k++) a += dn[b * 13 + k] * cls_W[k * 32 + l];
        aug[26][l] = f2bf(a);
    }
    for (int i = l; i < 192; i += 64) {
        int n = 27 + (i >> 5), d = i & 31;
        float s;
        if (i < 96) {
            size_t o = (size_t)b * 96 + i;
            s = p0[o] + p0[o + 786432] + p0[o + 2 * 786432] + p0[o + 3 * 786432] + fb0[i];
        } else {
            int j = i - 96; size_t o = (size_t)b * 96 + j;
            s = p1[o] + p1[o + 786432] + p1[o + 2 * 786432] + p1[o + 3 * 786432] + fb1[j];
        }
        aug[n][d] = f2bf(fast_tanh(s));
    }

    const int m16 = l & 15, quad = l >> 4;
    short8 a0 = *(const short8*)&aug[m16][quad * 8];
    short8 a1 = *(const short8*)&aug[16 + m16][quad * 8];
    f32x4 c00 = {}, c01 = {}, c11 = {};
    c00 = __builtin_amdgcn_mfma_f32_16x16x32_bf16(a0, a0, c00, 0, 0, 0);
    c01 = __builtin_amdgcn_mfma_f32_16x16x32_bf16(a0, a1, c01, 0, 0, 0);
    c11 = __builtin_amdgcn_mfma_f32_16x16x32_bf16(a1, a1, c11, 0, 0, 0);
    #pragma unroll
    for (int i = 0; i < 4; i++) {
        gram[quad * 4 + i][m16] = c00[i];
        gram[quad * 4 + i][16 + m16] = c01[i];
        gram[16 + quad * 4 + i][16 + m16] = c11[i];
    }
    if (l < 32) {
        float s = 0.f;
        #pragma unroll
        for (int kk = 0; kk < 16; kk++) {
            unsigned int x = *(const unsigned int*)&aug[l][2 * kk];
            unsigned int y = *(const unsigned int*)&aug[32][2 * kk];
            s += bf2f((bf16_t)(x & 0xFFFFu)) * bf2f((bf16_t)(y & 0xFFFFu));
            s += bf2f((bf16_t)(x >> 16)) * bf2f((bf16_t)(y >> 16));
        }
        gram[l][32] = s;
    }

    // stage full h row in LDS
    for (int idx = l; idx < 528; idx += 64)
        *(unsigned int*)&hrow[528 + 2 * idx] = *(const unsigned int*)&aug[idx >> 4][(idx & 15) * 2];
    if (l < 8) *(unsigned int*)&hrow[1584 + 2 * l] = 0u;
    for (int pp = l; pp < 264; pp += 64) {
        int p = 2 * pp;
        int i = (int)((65.0f - sqrtf(4225.0f - 8.0f * (float)p)) * 0.5f);
        int st = (i * (65 - i)) >> 1;
        if (st > p) { i--; st = (i * (65 - i)) >> 1; }
        else { int st2 = ((i + 1) * (64 - i)) >> 1; if (st2 <= p) { i++; st = st2; } }
        int j = i + 1 + (p - st);
        float s0, s1;
        if (j < 32) { s0 = gram[i][j]; s1 = gram[i][j + 1]; }
        else        { s0 = gram[i][32]; s1 = gram[i + 1][i + 2]; }
        *(unsigned int*)&hrow[p] = (unsigned int)f2bf(s0) | ((unsigned int)f2bf(s1) << 16);
    }
    // flush: 200 chunks of 16B
    bf16_t* hbp = h + ((size_t)(b >> 4) * 200) * 128 + (b & 15) * 8;
    for (int c = l; c < 200; c += 64) {
        uint4 v = *(const uint4*)&hrow[c * 8];
        *(uint4*)(hbp + (size_t)c * 128) = v;
    }
}

// ---------------------------------------------------------------------------
// K4: MLP, packed operands (unchanged).
// ---------------------------------------------------------------------------
__global__ __launch_bounds__(256) void k_mlp_mfma(
    const bf16_t* __restrict__ h, const bf16_t* __restrict__ Wt2,
    const float* __restrict__ b1, const float* __restrict__ gamma,
    const float* __restrict__ beta, const float* __restrict__ mean,
    const float* __restrict__ var, const float* __restrict__ outW,
    const float* __restrict__ outb, float* __restrict__ out)
{
    __shared__ float lds[2 * 16 * 65];
    __shared__ float red2[32];
    const int t = threadIdx.x, w = t >> 6, l = t & 63;
    const int lane15 = l & 15, quad = l >> 4;
    const int nhalf = w & 1, khalf = w >> 1;

    const bf16_t* ap = h + ((size_t)blockIdx.x * 200 + khalf * 100 + quad) * 128 + lane15 * 8;
    const bf16_t* bp = Wt2 + ((size_t)khalf * 25 * 8 + nhalf * 4) * 512 + l * 8;
    f32x4 acc[4] = {};

    #pragma unroll 2
    for (int it = 0; it < 25; it++) {
        short8 a = *(const short8*)(ap + it * 512);
        #pragma unroll
        for (int nt = 0; nt < 4; nt++) {
            short8 bf = *(const short8*)(bp + it * 4096 + nt * 512);
            acc[nt] = __builtin_amdgcn_mfma_f32_16x16x32_bf16(a, bf, acc[nt], 0, 0, 0);
        }
    }

    if (khalf == 1) {
        #pragma unroll
        for (int nt = 0; nt < 4; nt++)
            #pragma unroll
            for (int i = 0; i < 4; i++)
                lds[nhalf * 1040 + (quad * 4 + i) * 65 + nt * 16 + lane15] = acc[nt][i];
    }
    __syncthreads();
    if (khalf == 0) {
        float pl[4] = { 0.f, 0.f, 0.f, 0.f };
        #pragma unroll
        for (int nt = 0; nt < 4; nt++) {
            int c = nhalf * 64 + nt * 16 + lane15;
            float sc = gamma[c] * rsqrtf(var[c] + 1e-3f);
            float sh = beta[c] - mean[c] * sc;
            float ow = outW[c], bb = b1[c];
            #pragma unroll
            for (int i = 0; i < 4; i++) {
                float v = acc[nt][i] + lds[nhalf * 1040 + (quad * 4 + i) * 65 + nt * 16 + lane15] + bb;
                v = fmaxf(v, 0.f);
                pl[i] += (v * sc + sh) * ow;
            }
        }
        #pragma unroll
        for (int m = 1; m < 16; m <<= 1)
            #pragma unroll
            for (int i = 0; i < 4; i++) pl[i] += __shfl_xor(pl[i], m);
        if (lane15 == 0) {
            #pragma unroll
            for (int i = 0; i < 4; i++) red2[(quad * 4 + i) * 2 + nhalf] = pl[i];
        }
    }
    __syncthreads();
    if (t < 16) {
        float s = red2[t * 2] + red2[t * 2 + 1] + outb[0];
        out[blockIdx.x * 16 + t] = 1.f / (1.f + __expf(-s));
    }
}

// ---------------------------------------------------------------------------
extern "C" void kernel_launch(void* const* d_in, const int* in_sizes, int n_in,
                              void* d_out, int out_size, void* d_ws, size_t ws_size,
                              hipStream_t stream) {
    const int*   sp       = (const int*)d_in[0];
    const float* dn       = (const float*)d_in[1];
    const float* gen_tab  = (const float*)d_in[2];
    const float* gen_W    = (const float*)d_in[3];
    const float* gen_b    = (const float*)d_in[4];
    const float* cls_tab  = (const float*)d_in[5];
    const float* cls_W    = (const float*)d_in[6];
    const float* cls_b    = (const float*)d_in[7];
    const float* conv_k0  = (const float*)d_in[8];
    const float* conv_b0  = (const float*)d_in[9];
    const float* fc_W0    = (const float*)d_in[10];
    const float* fc_b0    = (const float*)d_in[11];
    const float* conv_k1  = (const float*)d_in[12];
    const float* conv_b1  = (const float*)d_in[13];
    const float* fc_W1    = (const float*)d_in[14];
    const float* fc_b1    = (const float*)d_in[15];
    const float* mlp_W1   = (const float*)d_in[16];
    const float* mlp_b1   = (const float*)d_in[17];
    const float* bn_gamma = (const float*)d_in[18];
    const float* bn_beta  = (const float*)d_in[19];
    const float* bn_mean  = (const float*)d_in[20];
    const float* bn_var   = (const float*)d_in[21];
    const float* out_W    = (const float*)d_in[22];
    const float* out_b    = (const float*)d_in[23];
    float* out = (float*)d_out;

    char* ws = (char*)d_ws;
    bf16_t* pooled0 = (bf16_t*)(ws + 0);
    bf16_t* pooled1 = (bf16_t*)(ws + 54525952ULL);
    float*  p0      = (float*)(ws + 79691776ULL);
    float*  p1      = (float*)(ws + 92274688ULL);
    bf16_t* Wt0     = (bf16_t*)(ws + 104857600ULL);
    bf16_t* Wt1     = (bf16_t*)(ws + 105496576ULL);
    bf16_t* Wt2     = (bf16_t*)(ws + 105791488ULL);
    bf16_t* h       = (bf16_t*)(ws + 0);   // aliases pooled0 (consumed by fc before build_h)

    k_wpack<<<dim3(1248, 3), 256, 0, stream>>>(fc_W0, fc_W1, mlp_W1, Wt0, Wt1, Wt2);
    k_conv_fused<<<BATCH / 2, 256, 0, stream>>>(sp, dn, gen_tab, gen_W, gen_b,
                                                conv_k0, conv_b0, conv_k1, conv_b1,
                                                pooled0, pooled1);
    k_fc_mfma<<<dim3(BATCH / 64, 4, 2), 256, 0, stream>>>(pooled0, Wt0, p0, pooled1, Wt1, p1);
    k_build_h<<<BATCH / 4, 256, 0, stream>>>(sp, dn, cls_tab, cls_W, cls_b,
                                             p0, fc_b0, p1, fc_b1, h);
    k_mlp_mfma<<<BATCH / 16, 256, 0, stream>>>(h, Wt2, mlp_b1, bn_gamma, bn_beta,
                                               bn_mean, bn_var, out_W, out_b, out);
}